// Round 12
// baseline (236.960 us; speedup 1.0000x reference)
//
#include <hip/hip_runtime.h>
#include <math.h>

#define THREADS 256
#define GT 512                    // gram block: 8 waves, 2 K-groups
#define BM 128
#define BK 32
#define EPSV 1e-5f
#define C1E 11.023176380641601f   // e^2.4
#define C2E 9.025013499434122f    // e^2.2

typedef short bf16x8 __attribute__((ext_vector_type(8)));   // 8 bf16 = 16 B
typedef float f32x4 __attribute__((ext_vector_type(4)));

// RNE float -> bf16 bit pattern
__device__ __forceinline__ unsigned short f2bf(float f) {
    unsigned int u = __float_as_uint(f);
    u += 0x7FFFu + ((u >> 16) & 1u);
    return (unsigned short)(u >> 16);
}

#define GLDS16(g, l)                                                          \
    __builtin_amdgcn_global_load_lds(                                         \
        (const __attribute__((address_space(1))) unsigned int*)(g),           \
        (__attribute__((address_space(3))) unsigned int*)(l), 16, 0, 0)

// ---------------------------------------------------------------------------
// Kernel A (sym path): NORMALIZE + convert. xb[row] = bf16(x[row]/||x[row]||).
// ---------------------------------------------------------------------------
__launch_bounds__(THREADS)
__global__ void norm_conv_kernel(const float* __restrict__ x,
                                 unsigned short* __restrict__ xb, int D) {
    const int row = blockIdx.x;
    const float4* x4 = (const float4*)(x + (size_t)row * D);
    const int tid = threadIdx.x;

    float s = 0.f;
    for (int b = tid * 2; b * 4 < D; b += THREADS * 2) {
        float4 v0 = x4[b];
        float4 v1 = x4[b + 1];
        s += v0.x * v0.x + v0.y * v0.y + v0.z * v0.z + v0.w * v0.w
           + v1.x * v1.x + v1.y * v1.y + v1.z * v1.z + v1.w * v1.w;
    }
#pragma unroll
    for (int off = 32; off > 0; off >>= 1) s += __shfl_down(s, off, 64);
    __shared__ float red[THREADS / 64 + 1];
    if ((tid & 63) == 0) red[tid >> 6] = s;
    __syncthreads();
    if (tid == 0) {
        float tot = 0.f;
#pragma unroll
        for (int w = 0; w < THREADS / 64; ++w) tot += red[w];
        red[THREADS / 64] = 1.0f / fmaxf(sqrtf(tot), 1e-12f);
    }
    __syncthreads();
    const float inv = red[THREADS / 64];

    bf16x8* out8 = (bf16x8*)(xb + (size_t)row * D);
    for (int b = tid * 2; b * 4 < D; b += THREADS * 2) {
        float4 v0 = x4[b];
        float4 v1 = x4[b + 1];
        bf16x8 o;
        o[0] = (short)f2bf(v0.x * inv); o[1] = (short)f2bf(v0.y * inv);
        o[2] = (short)f2bf(v0.z * inv); o[3] = (short)f2bf(v0.w * inv);
        o[4] = (short)f2bf(v1.x * inv); o[5] = (short)f2bf(v1.y * inv);
        o[6] = (short)f2bf(v1.z * inv); o[7] = (short)f2bf(v1.w * inv);
        out8[b >> 1] = o;
    }
}

// Plain inv-norm (fallback path).
__global__ void row_inv_norm_kernel(const float* __restrict__ x,
                                    float* __restrict__ inv_norm, int D) {
    const int row = blockIdx.x;
    const float4* x4 = (const float4*)(x + (size_t)row * D);
    const int nf4 = D >> 2;
    float s = 0.f;
    for (int i = threadIdx.x; i < nf4; i += THREADS) {
        float4 v = x4[i];
        s += v.x * v.x + v.y * v.y + v.z * v.z + v.w * v.w;
    }
#pragma unroll
    for (int off = 32; off > 0; off >>= 1) s += __shfl_down(s, off, 64);
    __shared__ float red[THREADS / 64];
    if ((threadIdx.x & 63) == 0) red[threadIdx.x >> 6] = s;
    __syncthreads();
    if (threadIdx.x == 0) {
        float tot = 0.f;
#pragma unroll
        for (int w = 0; w < THREADS / 64; ++w) tot += red[w];
        inv_norm[row] = 1.0f / fmaxf(sqrtf(tot), 1e-12f);
    }
}

// ---------------------------------------------------------------------------
// Kernel B: SYMMETRIC bf16 Gram, WAVE-LEVEL SPLIT-K.
// 512 threads = 8 waves = 2 K-groups x 4 waves. Group g computes the full
// 128x128 tile over K in [g*D/2, (g+1)*D/2) with the proven R8 single-buffer
// glds K-loop (32 iters). Partial dots combined via LDS (SoA, conflict-free
// b128); group 0 runs the R11 epilogue (no barriers there, group 1 retires).
// Doubles resident waves/CU (8.2 -> 16.5) and halves each serial K-chain —
// attacks the latency-bound plateau without growing ws or fetch traffic.
// vals: 0 s_pos_intra 1 cnt_pi 2 s_pos_cross 3 cnt_pc
//       4 DE_neg_intra 5 E_neg_intra 6 DE_neg_cross 7 E_neg_cross
// ---------------------------------------------------------------------------
__launch_bounds__(GT, 4)   // cap VGPR at 128: 4 waves/SIMD, 2 blocks/CU
__global__ void gram_sym_kernel(const unsigned short* __restrict__ xb,
                                const int* __restrict__ targets,
                                const int* __restrict__ sub,
                                float* __restrict__ pr,
                                float* __restrict__ pc,
                                int D) {
    __shared__ unsigned short As[2][BM * BK];   // [group][tile] 2 x 8 KB
    __shared__ unsigned short Bs[2][BM * BK];   // [group][tile] 2 x 8 KB

    // Triangular decode: tk = bx*(bx+1)/2 + by, by <= bx.
    const int tk = blockIdx.x;
    int bx = (int)((sqrtf(8.0f * tk + 1.0f) - 1.0f) * 0.5f);
    while ((bx + 1) * (bx + 2) / 2 <= tk) ++bx;
    while (bx * (bx + 1) / 2 > tk) --bx;
    const int by = tk - bx * (bx + 1) / 2;

    const int tid = threadIdx.x;
    const int w = tid >> 6;          // wave 0..7
    const int g = w >> 2;            // K-group 0/1
    const int wg = w & 3;            // wave within group
    const int lane = tid & 63;
    const int wm = wg & 1;           // row-half
    const int wn = wg >> 1;          // col-half
    const int quad = lane >> 4;
    const int cl = lane & 15;

    const int rowA0 = by * BM;
    const int colB0 = bx * BM;
    const int Dh = D >> 1;           // per-group K extent
    const unsigned short* Abase = xb + (size_t)rowA0 * D + g * Dh;
    const unsigned short* Bbase = xb + (size_t)colB0 * D + g * Dh;

    // glds staging (per group): 512 chunks of 16B per tile; wave wg, issue l
    // covers LDS chunks l*256 + wg*64 + lane; source chunk XOR-swizzled.
    const int ca0 = wg * 64 + lane;
    const int ca1 = 256 + wg * 64 + lane;
    const int r0 = ca0 >> 2, q0 = (ca0 & 3) ^ ((r0 >> 1) & 3);
    const int r1 = ca1 >> 2, q1 = (ca1 & 3) ^ ((r1 >> 1) & 3);
    const unsigned short* sA0 = Abase + (size_t)r0 * D + q0 * 8;
    const unsigned short* sA1 = Abase + (size_t)r1 * D + q1 * 8;
    const unsigned short* sB0 = Bbase + (size_t)r0 * D + q0 * 8;
    const unsigned short* sB1 = Bbase + (size_t)r1 * D + q1 * 8;
    unsigned short* dA0 = &As[g][(wg * 64) * 8];      // wave-uniform bases
    unsigned short* dA1 = &As[g][(256 + wg * 64) * 8];
    unsigned short* dB0 = &Bs[g][(wg * 64) * 8];
    unsigned short* dB1 = &Bs[g][(256 + wg * 64) * 8];

    f32x4 accv[4][4];
#pragma unroll
    for (int i = 0; i < 4; ++i)
#pragma unroll
        for (int j = 0; j < 4; ++j) accv[i][j] = (f32x4)(0.f);

    // Fragment read offsets (tile-local), swizzled: q' = quad ^ ((row>>1)&3).
    int aoff[4], boff[4];
#pragma unroll
    for (int f = 0; f < 4; ++f) {
        const int ar = wm * 64 + f * 16 + cl;
        aoff[f] = ar * BK + (quad ^ ((ar >> 1) & 3)) * 8;
        const int br = wn * 64 + f * 16 + cl;
        boff[f] = br * BK + (quad ^ ((br >> 1) & 3)) * 8;
    }

    for (int kb = 0; kb < Dh; kb += BK) {
        GLDS16(sA0 + kb, dA0);
        GLDS16(sA1 + kb, dA1);
        GLDS16(sB0 + kb, dB0);
        GLDS16(sB1 + kb, dB1);
        __syncthreads();   // drains vmcnt: both groups' tiles in LDS

        bf16x8 af[4], bfv[4];
#pragma unroll
        for (int f = 0; f < 4; ++f) {
            af[f] = *(const bf16x8*)&As[g][aoff[f]];
            bfv[f] = *(const bf16x8*)&Bs[g][boff[f]];
        }
#pragma unroll
        for (int mi = 0; mi < 4; ++mi)
#pragma unroll
            for (int ni = 0; ni < 4; ++ni)
                accv[mi][ni] = __builtin_amdgcn_mfma_f32_16x16x32_bf16(
                    af[mi], bfv[ni], accv[mi][ni], 0, 0, 0);
        __syncthreads();   // tiles consumed
    }

    // ---- combine K-group partials: group1 -> LDS (SoA) -> group0 adds ----
#pragma unroll
    for (int h = 0; h < 2; ++h) {
        if (g == 1) {
            const int t2 = tid - 256;
            f32x4* bufA = (f32x4*)&As[0][0];   // 16 KB = 1024 f32x4
            f32x4* bufB = (f32x4*)&Bs[0][0];
#pragma unroll
            for (int ni = 0; ni < 4; ++ni) {
                bufA[ni * 256 + t2] = accv[2 * h][ni];
                bufB[ni * 256 + t2] = accv[2 * h + 1][ni];
            }
        }
        __syncthreads();
        if (g == 0) {
            f32x4* bufA = (f32x4*)&As[0][0];
            f32x4* bufB = (f32x4*)&Bs[0][0];
#pragma unroll
            for (int ni = 0; ni < 4; ++ni) {
                accv[2 * h][ni] += bufA[ni * 256 + tid];
                accv[2 * h + 1][ni] += bufB[ni * 256 + tid];
            }
        }
        __syncthreads();
    }
    if (g == 1) return;   // no barriers below: safe retire

    // ---------------- epilogue pass 1: dd + row partials ----------------
    // C/D map: col = cl, row = quad*4 + reg. (group 0 only, tid 0..255)
    int tj[4], sj[4];
#pragma unroll
    for (int ni = 0; ni < 4; ++ni) {
        const int gc = colB0 + wn * 64 + ni * 16 + cl;
        tj[ni] = targets[gc];
        sj[ni] = sub[gc];
    }

#pragma unroll
    for (int mi = 0; mi < 4; ++mi) {
#pragma unroll
        for (int r = 0; r < 4; ++r) {
            const int gi = rowA0 + wm * 64 + mi * 16 + quad * 4 + r;
            const int ti = targets[gi];
            const int si = sub[gi];

            float s0 = 0.f, s1 = 0.f, s2 = 0.f, s3 = 0.f;
            float s4 = 0.f, s5 = 0.f, s6 = 0.f, s7 = 0.f;
#pragma unroll
            for (int ni = 0; ni < 4; ++ni) {
                const int gj = colB0 + wn * 64 + ni * 16 + cl;
                const float d2 = fmaf(-2.f, accv[mi][ni][r], 2.f);
                const float dd = sqrtf(fmaxf(d2, 1e-12f));
                accv[mi][ni][r] = dd;          // overwrite: pass 2 reuses
                const bool same = (ti == tj[ni]);
                const bool intra = (si == sj[ni]);
                const bool pos = same && (gi != gj);
                const bool neg = !same;
                const float mg = intra ? 1.4f : 0.7f;
                const float v = fmaxf(dd - mg, 0.f);
                const float e = __expf(-dd);   // e^alpha folded in finalize
                const float de = dd * e;
                if (pos && intra)  { s0 += v;  s1 += 1.f; }
                if (pos && !intra) { s2 += v;  s3 += 1.f; }
                if (neg && intra)  { s4 += de; s5 += e; }
                if (neg && !intra) { s6 += de; s7 += e; }
            }
#pragma unroll
            for (int off = 1; off < 16; off <<= 1) {
                s0 += __shfl_xor(s0, off, 64);
                s1 += __shfl_xor(s1, off, 64);
                s2 += __shfl_xor(s2, off, 64);
                s3 += __shfl_xor(s3, off, 64);
                s4 += __shfl_xor(s4, off, 64);
                s5 += __shfl_xor(s5, off, 64);
                s6 += __shfl_xor(s6, off, 64);
                s7 += __shfl_xor(s7, off, 64);
            }
            if (cl == 0) {
                const int rloc = wm * 64 + mi * 16 + quad * 4 + r;
                float* dst = pr +
                    ((size_t)(blockIdx.x * 2 + wn) * 128 + rloc) * 8;
                float4 p0 = {s0, s1, s2, s3};
                float4 p1 = {s4, s5, s6, s7};
                *(float4*)(dst) = p0;
                *(float4*)(dst + 4) = p1;
            }
        }
    }

    // ---------------- epilogue pass 2: col partials ----------------
    const float om = (bx == by) ? 0.f : 1.f;   // diag tiles: zero col side
#pragma unroll
    for (int ni = 0; ni < 4; ++ni) {
        const int gj = colB0 + wn * 64 + ni * 16 + cl;
        const int tjc = tj[ni];
        const int sjc = sj[ni];
        float s0 = 0.f, s1 = 0.f, s2 = 0.f, s3 = 0.f;
        float s4 = 0.f, s5 = 0.f, s6 = 0.f, s7 = 0.f;
#pragma unroll
        for (int mi = 0; mi < 4; ++mi) {
#pragma unroll
            for (int r = 0; r < 4; ++r) {
                const int gi = rowA0 + wm * 64 + mi * 16 + quad * 4 + r;
                const int ti = targets[gi];     // L1-hot reload
                const int si = sub[gi];
                const float dd = accv[mi][ni][r];
                const bool same = (ti == tjc);
                const bool intra = (si == sjc);
                const bool pos = same && (gi != gj);
                const bool neg = !same;
                const float mg = intra ? 1.4f : 0.7f;
                const float v = fmaxf(dd - mg, 0.f);
                const float e = __expf(-dd);
                const float de = dd * e;
                if (pos && intra)  { s0 += v;  s1 += 1.f; }
                if (pos && !intra) { s2 += v;  s3 += 1.f; }
                if (neg && intra)  { s4 += de; s5 += e; }
                if (neg && !intra) { s6 += de; s7 += e; }
            }
        }
        s0 += __shfl_xor(s0, 16, 64); s0 += __shfl_xor(s0, 32, 64);
        s1 += __shfl_xor(s1, 16, 64); s1 += __shfl_xor(s1, 32, 64);
        s2 += __shfl_xor(s2, 16, 64); s2 += __shfl_xor(s2, 32, 64);
        s3 += __shfl_xor(s3, 16, 64); s3 += __shfl_xor(s3, 32, 64);
        s4 += __shfl_xor(s4, 16, 64); s4 += __shfl_xor(s4, 32, 64);
        s5 += __shfl_xor(s5, 16, 64); s5 += __shfl_xor(s5, 32, 64);
        s6 += __shfl_xor(s6, 16, 64); s6 += __shfl_xor(s6, 32, 64);
        s7 += __shfl_xor(s7, 16, 64); s7 += __shfl_xor(s7, 32, 64);
        if (lane < 16) {
            const int colloc = wn * 64 + ni * 16 + lane;
            float* dst = pc +
                ((size_t)(blockIdx.x * 2 + wm) * 128 + colloc) * 8;
            float4 p0 = {s0 * om, s1 * om, s2 * om, s3 * om};
            float4 p1 = {s4 * om, s5 * om, s6 * om, s7 * om};
            *(float4*)(dst) = p0;
            *(float4*)(dst + 4) = p1;
        }
    }
}

// ---------------------------------------------------------------------------
// Kernel C: gather 64 slices per row, combine ratios, global mean.
// ---------------------------------------------------------------------------
__global__ void finalize_sym_kernel(const float* __restrict__ pr,
                                    const float* __restrict__ pc,
                                    float* __restrict__ out, int N, int nbx) {
    const int tid = threadIdx.x;
    const int rloc16 = tid >> 4;
    const int st = tid & 15;
    const int i = blockIdx.x * 16 + rloc16;
    const int B = i >> 7;
    const int rl = i & 127;
    const int nrow = (nbx - B) * 2;

    float a0 = 0.f, a1 = 0.f, a2 = 0.f, a3 = 0.f;
    float a4 = 0.f, a5 = 0.f, a6 = 0.f, a7 = 0.f;
#pragma unroll
    for (int s4i = 0; s4i < 4; ++s4i) {
        const int sidx = st * 4 + s4i;
        const float* base;
        if (sidx < nrow) {
            const int bxx = B + (sidx >> 1);
            const int t = bxx * (bxx + 1) / 2 + B;
            base = pr + ((size_t)(t * 2 + (sidx & 1)) * 128 + rl) * 8;
        } else {
            const int m = sidx - nrow;
            const int t = B * (B + 1) / 2 + (m >> 1);
            base = pc + ((size_t)(t * 2 + (m & 1)) * 128 + rl) * 8;
        }
        float4 u0 = *(const float4*)(base);
        float4 u1 = *(const float4*)(base + 4);
        a0 += u0.x; a1 += u0.y; a2 += u0.z; a3 += u0.w;
        a4 += u1.x; a5 += u1.y; a6 += u1.z; a7 += u1.w;
    }
#pragma unroll
    for (int off = 1; off < 16; off <<= 1) {
        a0 += __shfl_xor(a0, off, 64);
        a1 += __shfl_xor(a1, off, 64);
        a2 += __shfl_xor(a2, off, 64);
        a3 += __shfl_xor(a3, off, 64);
        a4 += __shfl_xor(a4, off, 64);
        a5 += __shfl_xor(a5, off, 64);
        a6 += __shfl_xor(a6, off, 64);
        a7 += __shfl_xor(a7, off, 64);
    }
    __shared__ float lred[16];
    if (st == 0) {
        const float l = a0 / (a1 + EPSV) + a2 / (a3 + EPSV)
            + (C1E * fmaf(2.4f, a5, -a4)) / (C1E * a5 + EPSV)
            + (C2E * fmaf(2.2f, a7, -a6)) / (C2E * a7 + EPSV);
        lred[rloc16] = l;
    }
    __syncthreads();
    if (tid == 0) {
        float tot = 0.f;
#pragma unroll
        for (int k2 = 0; k2 < 16; ++k2) tot += lred[k2];
        atomicAdd(out, tot / (float)N);
    }
}

// ---------------------------------------------------------------------------
// Fallback path (144 KB ws): fp32 tile GEMM + atomic epilogue (R1, known-good)
// ---------------------------------------------------------------------------
__launch_bounds__(THREADS, 2)
__global__ void dist_loss_kernel(const float* __restrict__ x,
                                 const int* __restrict__ targets,
                                 const int* __restrict__ sub,
                                 const float* __restrict__ inv_norm,
                                 float* __restrict__ acc,
                                 int N, int D) {
    __shared__ float Asf[16][128];
    __shared__ float Bsf[16][128];

    const int nbx = N / 128;
    const int bx = blockIdx.x % nbx;
    const int by = blockIdx.x / nbx;
    const int tid = threadIdx.x;
    const int tx = tid & 15;
    const int ty = tid >> 4;
    const int rowA0 = by * 128;
    const int colB0 = bx * 128;
    const float* Abase = x + (size_t)rowA0 * D;
    const float* Bbase = x + (size_t)colB0 * D;

    float accv[8][8];
#pragma unroll
    for (int r = 0; r < 8; ++r)
#pragma unroll
        for (int c = 0; c < 8; ++c) accv[r][c] = 0.f;

    for (int kb = 0; kb < D; kb += 16) {
#pragma unroll
        for (int l = 0; l < 2; ++l) {
            const int f = tid + l * THREADS;
            const int row = f >> 2;
            const int kq = (f & 3) << 2;
            float4 va = *(const float4*)(Abase + (size_t)row * D + kb + kq);
            float4 vb = *(const float4*)(Bbase + (size_t)row * D + kb + kq);
            Asf[kq + 0][row] = va.x; Asf[kq + 1][row] = va.y;
            Asf[kq + 2][row] = va.z; Asf[kq + 3][row] = va.w;
            Bsf[kq + 0][row] = vb.x; Bsf[kq + 1][row] = vb.y;
            Bsf[kq + 2][row] = vb.z; Bsf[kq + 3][row] = vb.w;
        }
        __syncthreads();
#pragma unroll
        for (int k = 0; k < 16; ++k) {
            float4 a0 = *(const float4*)&Asf[k][ty * 8];
            float4 a1 = *(const float4*)&Asf[k][ty * 8 + 4];
            float4 b0 = *(const float4*)&Bsf[k][tx * 8];
            float4 b1 = *(const float4*)&Bsf[k][tx * 8 + 4];
            float ar[8] = {a0.x, a0.y, a0.z, a0.w, a1.x, a1.y, a1.z, a1.w};
            float br[8] = {b0.x, b0.y, b0.z, b0.w, b1.x, b1.y, b1.z, b1.w};
#pragma unroll
            for (int r = 0; r < 8; ++r)
#pragma unroll
                for (int c = 0; c < 8; ++c)
                    accv[r][c] = fmaf(ar[r], br[c], accv[r][c]);
        }
        __syncthreads();
    }

    const int row_base = rowA0 + ty * 8;
    const int col_base = colB0 + tx * 8;
    int tjc[8], sjc[8];
    float invj[8];
#pragma unroll
    for (int c = 0; c < 8; ++c) {
        tjc[c] = targets[col_base + c];
        sjc[c] = sub[col_base + c];
        invj[c] = inv_norm[col_base + c];
    }
#pragma unroll
    for (int r = 0; r < 8; ++r) {
        const int gi = row_base + r;
        const int ti = targets[gi];
        const int si = sub[gi];
        const float invi = inv_norm[gi];
        float s0 = 0.f, s1 = 0.f, s2 = 0.f, s3 = 0.f;
        float s4 = 0.f, s5 = 0.f, s6 = 0.f, s7 = 0.f;
#pragma unroll
        for (int c = 0; c < 8; ++c) {
            const int gj = col_base + c;
            const float dot = accv[r][c] * invi * invj[c];
            const float dd = sqrtf(fmaxf(2.f - 2.f * dot, 1e-12f));
            const bool same = (ti == tjc[c]);
            const bool intra = (si == sjc[c]);
            const bool pos = same && (gi != gj);
            const bool neg = !same;
            const float df = (intra ? 2.4f : 2.2f) - dd;
            const float wgt = __expf(df);
            const float v = fmaxf(dd - (intra ? 1.4f : 0.7f), 0.f);
            if (pos && intra)  { s0 += v; s1 += 1.f; }
            if (pos && !intra) { s2 += v; s3 += 1.f; }
            if (neg && intra)  { s4 += df * wgt; s5 += wgt; }
            if (neg && !intra) { s6 += df * wgt; s7 += wgt; }
        }
#pragma unroll
        for (int off = 1; off < 16; off <<= 1) {
            s0 += __shfl_xor(s0, off, 64);
            s1 += __shfl_xor(s1, off, 64);
            s2 += __shfl_xor(s2, off, 64);
            s3 += __shfl_xor(s3, off, 64);
            s4 += __shfl_xor(s4, off, 64);
            s5 += __shfl_xor(s5, off, 64);
            s6 += __shfl_xor(s6, off, 64);
            s7 += __shfl_xor(s7, off, 64);
        }
        if (tx == 0) {
            float* a = acc + (size_t)gi * 8;
            atomicAdd(a + 0, s0); atomicAdd(a + 1, s1);
            atomicAdd(a + 2, s2); atomicAdd(a + 3, s3);
            atomicAdd(a + 4, s4); atomicAdd(a + 5, s5);
            atomicAdd(a + 6, s6); atomicAdd(a + 7, s7);
        }
    }
}

__global__ void finalize_kernel(const float* __restrict__ acc,
                                float* __restrict__ out, int N) {
    float s = 0.f;
    for (int i = threadIdx.x; i < N; i += THREADS) {
        const float* a = acc + (size_t)i * 8;
        s += a[0] / (a[1] + EPSV) + a[2] / (a[3] + EPSV)
           + a[4] / (a[5] + EPSV) + a[6] / (a[7] + EPSV);
    }
#pragma unroll
    for (int off = 32; off > 0; off >>= 1) s += __shfl_down(s, off, 64);
    __shared__ float red[THREADS / 64];
    if ((threadIdx.x & 63) == 0) red[threadIdx.x >> 6] = s;
    __syncthreads();
    if (threadIdx.x == 0) {
        float tot = 0.f;
#pragma unroll
        for (int w = 0; w < THREADS / 64; ++w) tot += red[w];
        out[0] = tot / (float)N;
    }
}

// ---------------------------------------------------------------------------
extern "C" void kernel_launch(void* const* d_in, const int* in_sizes, int n_in,
                              void* d_out, int out_size, void* d_ws, size_t ws_size,
                              hipStream_t stream) {
    const float* x = (const float*)d_in[0];
    const int* targets = (const int*)d_in[1];
    const int* sub = (const int*)d_in[2];
    const int N = in_sizes[1];
    const int D = in_sizes[0] / N;

    const int nbx = N / BM;
    const int T = nbx * (nbx + 1) / 2;
    const size_t sliceB = (size_t)T * 2 * 128 * 8 * sizeof(float);
    const size_t need = (size_t)N * D * 2 + 2 * sliceB;

    if (ws_size >= need) {
        unsigned short* xb = (unsigned short*)d_ws;           // N*D bf16
        float* pr = (float*)((char*)d_ws + (size_t)N * D * 2);
        float* pc = pr + (size_t)T * 2 * 128 * 8;

        hipMemsetAsync(d_out, 0, sizeof(float), stream);
        norm_conv_kernel<<<N, THREADS, 0, stream>>>(x, xb, D);
        gram_sym_kernel<<<T, GT, 0, stream>>>(xb, targets, sub, pr, pc, D);
        finalize_sym_kernel<<<N / 16, THREADS, 0, stream>>>(
            pr, pc, (float*)d_out, N, nbx);
    } else {
        // Fallback (144 KB ws): fp32 path, known-good from round 1.
        float* inv_norm = (float*)d_ws;
        float* acc = inv_norm + N;
        hipMemsetAsync(acc, 0, (size_t)N * 8 * sizeof(float), stream);
        row_inv_norm_kernel<<<N, THREADS, 0, stream>>>(x, inv_norm, D);
        dist_loss_kernel<<<nbx * nbx, THREADS, 0, stream>>>(
            x, targets, sub, inv_norm, acc, N, D);
        finalize_kernel<<<1, THREADS, 0, stream>>>(acc, (float*)d_out, N);
    }
}

// Round 13
// 220.626 us; speedup vs baseline: 1.0740x; 1.0740x over previous
//
#include <hip/hip_runtime.h>
#include <math.h>

#define THREADS 256
#define GT 512                    // gram block: 8 waves, 2 K-groups
#define BM 128
#define BK 32
#define EPSV 1e-5f
#define C1E 11.023176380641601f   // e^2.4
#define C2E 9.025013499434122f    // e^2.2

typedef short bf16x8 __attribute__((ext_vector_type(8)));   // 8 bf16 = 16 B
typedef float f32x4 __attribute__((ext_vector_type(4)));

// RNE float -> bf16 bit pattern
__device__ __forceinline__ unsigned short f2bf(float f) {
    unsigned int u = __float_as_uint(f);
    u += 0x7FFFu + ((u >> 16) & 1u);
    return (unsigned short)(u >> 16);
}

#define GLDS16(g, l)                                                          \
    __builtin_amdgcn_global_load_lds(                                         \
        (const __attribute__((address_space(1))) unsigned int*)(g),           \
        (__attribute__((address_space(3))) unsigned int*)(l), 16, 0, 0)

// ---------------------------------------------------------------------------
// Kernel A (sym path): NORMALIZE + convert. xb[row] = bf16(x[row]/||x[row]||).
// ---------------------------------------------------------------------------
__launch_bounds__(THREADS)
__global__ void norm_conv_kernel(const float* __restrict__ x,
                                 unsigned short* __restrict__ xb, int D) {
    const int row = blockIdx.x;
    const float4* x4 = (const float4*)(x + (size_t)row * D);
    const int tid = threadIdx.x;

    float s = 0.f;
    for (int b = tid * 2; b * 4 < D; b += THREADS * 2) {
        float4 v0 = x4[b];
        float4 v1 = x4[b + 1];
        s += v0.x * v0.x + v0.y * v0.y + v0.z * v0.z + v0.w * v0.w
           + v1.x * v1.x + v1.y * v1.y + v1.z * v1.z + v1.w * v1.w;
    }
#pragma unroll
    for (int off = 32; off > 0; off >>= 1) s += __shfl_down(s, off, 64);
    __shared__ float red[THREADS / 64 + 1];
    if ((tid & 63) == 0) red[tid >> 6] = s;
    __syncthreads();
    if (tid == 0) {
        float tot = 0.f;
#pragma unroll
        for (int w = 0; w < THREADS / 64; ++w) tot += red[w];
        red[THREADS / 64] = 1.0f / fmaxf(sqrtf(tot), 1e-12f);
    }
    __syncthreads();
    const float inv = red[THREADS / 64];

    bf16x8* out8 = (bf16x8*)(xb + (size_t)row * D);
    for (int b = tid * 2; b * 4 < D; b += THREADS * 2) {
        float4 v0 = x4[b];
        float4 v1 = x4[b + 1];
        bf16x8 o;
        o[0] = (short)f2bf(v0.x * inv); o[1] = (short)f2bf(v0.y * inv);
        o[2] = (short)f2bf(v0.z * inv); o[3] = (short)f2bf(v0.w * inv);
        o[4] = (short)f2bf(v1.x * inv); o[5] = (short)f2bf(v1.y * inv);
        o[6] = (short)f2bf(v1.z * inv); o[7] = (short)f2bf(v1.w * inv);
        out8[b >> 1] = o;
    }
}

// Plain inv-norm (fallback path).
__global__ void row_inv_norm_kernel(const float* __restrict__ x,
                                    float* __restrict__ inv_norm, int D) {
    const int row = blockIdx.x;
    const float4* x4 = (const float4*)(x + (size_t)row * D);
    const int nf4 = D >> 2;
    float s = 0.f;
    for (int i = threadIdx.x; i < nf4; i += THREADS) {
        float4 v = x4[i];
        s += v.x * v.x + v.y * v.y + v.z * v.z + v.w * v.w;
    }
#pragma unroll
    for (int off = 32; off > 0; off >>= 1) s += __shfl_down(s, off, 64);
    __shared__ float red[THREADS / 64];
    if ((threadIdx.x & 63) == 0) red[threadIdx.x >> 6] = s;
    __syncthreads();
    if (threadIdx.x == 0) {
        float tot = 0.f;
#pragma unroll
        for (int w = 0; w < THREADS / 64; ++w) tot += red[w];
        inv_norm[row] = 1.0f / fmaxf(sqrtf(tot), 1e-12f);
    }
}

// ---------------------------------------------------------------------------
// Kernel B: SYMMETRIC bf16 Gram, WAVE-LEVEL SPLIT-K (R12 structure).
// R13 fix: __launch_bounds__(512, 2). R12's (512,4) was interpreted as
// CUDA-style min-BLOCKS-per-CU (4 blk x 8 waves = 32 waves/CU -> 64-VGPR cap
// -> 68 MB of K-loop scratch spill, the whole regression). (512,2) = 2
// blocks/CU = 16 waves/CU -> 128-VGPR cap; per-thread state ~124 fits.
// vals: 0 s_pos_intra 1 cnt_pi 2 s_pos_cross 3 cnt_pc
//       4 DE_neg_intra 5 E_neg_intra 6 DE_neg_cross 7 E_neg_cross
// ---------------------------------------------------------------------------
__launch_bounds__(GT, 2)   // 2 blocks/CU: 16 waves/CU, VGPR cap 128 (no spill)
__global__ void gram_sym_kernel(const unsigned short* __restrict__ xb,
                                const int* __restrict__ targets,
                                const int* __restrict__ sub,
                                float* __restrict__ pr,
                                float* __restrict__ pc,
                                int D) {
    __shared__ unsigned short As[2][BM * BK];   // [group][tile] 2 x 8 KB
    __shared__ unsigned short Bs[2][BM * BK];   // [group][tile] 2 x 8 KB

    // Triangular decode: tk = bx*(bx+1)/2 + by, by <= bx.
    const int tk = blockIdx.x;
    int bx = (int)((sqrtf(8.0f * tk + 1.0f) - 1.0f) * 0.5f);
    while ((bx + 1) * (bx + 2) / 2 <= tk) ++bx;
    while (bx * (bx + 1) / 2 > tk) --bx;
    const int by = tk - bx * (bx + 1) / 2;

    const int tid = threadIdx.x;
    const int w = tid >> 6;          // wave 0..7
    const int g = w >> 2;            // K-group 0/1
    const int wg = w & 3;            // wave within group
    const int lane = tid & 63;
    const int wm = wg & 1;           // row-half
    const int wn = wg >> 1;          // col-half
    const int quad = lane >> 4;
    const int cl = lane & 15;

    const int rowA0 = by * BM;
    const int colB0 = bx * BM;
    const int Dh = D >> 1;           // per-group K extent
    const unsigned short* Abase = xb + (size_t)rowA0 * D + g * Dh;
    const unsigned short* Bbase = xb + (size_t)colB0 * D + g * Dh;

    // glds staging (per group): 512 chunks of 16B per tile; wave wg, issue l
    // covers LDS chunks l*256 + wg*64 + lane; source chunk XOR-swizzled.
    const int ca0 = wg * 64 + lane;
    const int ca1 = 256 + wg * 64 + lane;
    const int r0 = ca0 >> 2, q0 = (ca0 & 3) ^ ((r0 >> 1) & 3);
    const int r1 = ca1 >> 2, q1 = (ca1 & 3) ^ ((r1 >> 1) & 3);
    const unsigned short* sA0 = Abase + (size_t)r0 * D + q0 * 8;
    const unsigned short* sA1 = Abase + (size_t)r1 * D + q1 * 8;
    const unsigned short* sB0 = Bbase + (size_t)r0 * D + q0 * 8;
    const unsigned short* sB1 = Bbase + (size_t)r1 * D + q1 * 8;
    unsigned short* dA0 = &As[g][(wg * 64) * 8];      // wave-uniform bases
    unsigned short* dA1 = &As[g][(256 + wg * 64) * 8];
    unsigned short* dB0 = &Bs[g][(wg * 64) * 8];
    unsigned short* dB1 = &Bs[g][(256 + wg * 64) * 8];

    f32x4 accv[4][4];
#pragma unroll
    for (int i = 0; i < 4; ++i)
#pragma unroll
        for (int j = 0; j < 4; ++j) accv[i][j] = (f32x4)(0.f);

    // Fragment read offsets (tile-local), swizzled: q' = quad ^ ((row>>1)&3).
    int aoff[4], boff[4];
#pragma unroll
    for (int f = 0; f < 4; ++f) {
        const int ar = wm * 64 + f * 16 + cl;
        aoff[f] = ar * BK + (quad ^ ((ar >> 1) & 3)) * 8;
        const int br = wn * 64 + f * 16 + cl;
        boff[f] = br * BK + (quad ^ ((br >> 1) & 3)) * 8;
    }

    for (int kb = 0; kb < Dh; kb += BK) {
        GLDS16(sA0 + kb, dA0);
        GLDS16(sA1 + kb, dA1);
        GLDS16(sB0 + kb, dB0);
        GLDS16(sB1 + kb, dB1);
        __syncthreads();   // drains vmcnt: both groups' tiles in LDS

        bf16x8 af[4], bfv[4];
#pragma unroll
        for (int f = 0; f < 4; ++f) {
            af[f] = *(const bf16x8*)&As[g][aoff[f]];
            bfv[f] = *(const bf16x8*)&Bs[g][boff[f]];
        }
#pragma unroll
        for (int mi = 0; mi < 4; ++mi)
#pragma unroll
            for (int ni = 0; ni < 4; ++ni)
                accv[mi][ni] = __builtin_amdgcn_mfma_f32_16x16x32_bf16(
                    af[mi], bfv[ni], accv[mi][ni], 0, 0, 0);
        __syncthreads();   // tiles consumed
    }

    // ---- combine K-group partials: group1 -> LDS (SoA) -> group0 adds ----
#pragma unroll
    for (int h = 0; h < 2; ++h) {
        if (g == 1) {
            const int t2 = tid - 256;
            f32x4* bufA = (f32x4*)&As[0][0];   // 16 KB = 1024 f32x4
            f32x4* bufB = (f32x4*)&Bs[0][0];
#pragma unroll
            for (int ni = 0; ni < 4; ++ni) {
                bufA[ni * 256 + t2] = accv[2 * h][ni];
                bufB[ni * 256 + t2] = accv[2 * h + 1][ni];
            }
        }
        __syncthreads();
        if (g == 0) {
            f32x4* bufA = (f32x4*)&As[0][0];
            f32x4* bufB = (f32x4*)&Bs[0][0];
#pragma unroll
            for (int ni = 0; ni < 4; ++ni) {
                accv[2 * h][ni] += bufA[ni * 256 + tid];
                accv[2 * h + 1][ni] += bufB[ni * 256 + tid];
            }
        }
        __syncthreads();
    }
    if (g == 1) return;   // no barriers below: safe retire

    // ---------------- epilogue pass 1: dd + row partials ----------------
    // C/D map: col = cl, row = quad*4 + reg. (group 0 only, tid 0..255)
    int tj[4], sj[4];
#pragma unroll
    for (int ni = 0; ni < 4; ++ni) {
        const int gc = colB0 + wn * 64 + ni * 16 + cl;
        tj[ni] = targets[gc];
        sj[ni] = sub[gc];
    }

#pragma unroll
    for (int mi = 0; mi < 4; ++mi) {
#pragma unroll
        for (int r = 0; r < 4; ++r) {
            const int gi = rowA0 + wm * 64 + mi * 16 + quad * 4 + r;
            const int ti = targets[gi];
            const int si = sub[gi];

            float s0 = 0.f, s1 = 0.f, s2 = 0.f, s3 = 0.f;
            float s4 = 0.f, s5 = 0.f, s6 = 0.f, s7 = 0.f;
#pragma unroll
            for (int ni = 0; ni < 4; ++ni) {
                const int gj = colB0 + wn * 64 + ni * 16 + cl;
                const float d2 = fmaf(-2.f, accv[mi][ni][r], 2.f);
                const float dd = sqrtf(fmaxf(d2, 1e-12f));
                accv[mi][ni][r] = dd;          // overwrite: pass 2 reuses
                const bool same = (ti == tj[ni]);
                const bool intra = (si == sj[ni]);
                const bool pos = same && (gi != gj);
                const bool neg = !same;
                const float mg = intra ? 1.4f : 0.7f;
                const float v = fmaxf(dd - mg, 0.f);
                const float e = __expf(-dd);   // e^alpha folded in finalize
                const float de = dd * e;
                if (pos && intra)  { s0 += v;  s1 += 1.f; }
                if (pos && !intra) { s2 += v;  s3 += 1.f; }
                if (neg && intra)  { s4 += de; s5 += e; }
                if (neg && !intra) { s6 += de; s7 += e; }
            }
#pragma unroll
            for (int off = 1; off < 16; off <<= 1) {
                s0 += __shfl_xor(s0, off, 64);
                s1 += __shfl_xor(s1, off, 64);
                s2 += __shfl_xor(s2, off, 64);
                s3 += __shfl_xor(s3, off, 64);
                s4 += __shfl_xor(s4, off, 64);
                s5 += __shfl_xor(s5, off, 64);
                s6 += __shfl_xor(s6, off, 64);
                s7 += __shfl_xor(s7, off, 64);
            }
            if (cl == 0) {
                const int rloc = wm * 64 + mi * 16 + quad * 4 + r;
                float* dst = pr +
                    ((size_t)(blockIdx.x * 2 + wn) * 128 + rloc) * 8;
                float4 p0 = {s0, s1, s2, s3};
                float4 p1 = {s4, s5, s6, s7};
                *(float4*)(dst) = p0;
                *(float4*)(dst + 4) = p1;
            }
        }
    }

    // ---------------- epilogue pass 2: col partials ----------------
    const float om = (bx == by) ? 0.f : 1.f;   // diag tiles: zero col side
#pragma unroll
    for (int ni = 0; ni < 4; ++ni) {
        const int gj = colB0 + wn * 64 + ni * 16 + cl;
        const int tjc = tj[ni];
        const int sjc = sj[ni];
        float s0 = 0.f, s1 = 0.f, s2 = 0.f, s3 = 0.f;
        float s4 = 0.f, s5 = 0.f, s6 = 0.f, s7 = 0.f;
#pragma unroll
        for (int mi = 0; mi < 4; ++mi) {
#pragma unroll
            for (int r = 0; r < 4; ++r) {
                const int gi = rowA0 + wm * 64 + mi * 16 + quad * 4 + r;
                const int ti = targets[gi];     // L1-hot reload
                const int si = sub[gi];
                const float dd = accv[mi][ni][r];
                const bool same = (ti == tjc);
                const bool intra = (si == sjc);
                const bool pos = same && (gi != gj);
                const bool neg = !same;
                const float mg = intra ? 1.4f : 0.7f;
                const float v = fmaxf(dd - mg, 0.f);
                const float e = __expf(-dd);
                const float de = dd * e;
                if (pos && intra)  { s0 += v;  s1 += 1.f; }
                if (pos && !intra) { s2 += v;  s3 += 1.f; }
                if (neg && intra)  { s4 += de; s5 += e; }
                if (neg && !intra) { s6 += de; s7 += e; }
            }
        }
        s0 += __shfl_xor(s0, 16, 64); s0 += __shfl_xor(s0, 32, 64);
        s1 += __shfl_xor(s1, 16, 64); s1 += __shfl_xor(s1, 32, 64);
        s2 += __shfl_xor(s2, 16, 64); s2 += __shfl_xor(s2, 32, 64);
        s3 += __shfl_xor(s3, 16, 64); s3 += __shfl_xor(s3, 32, 64);
        s4 += __shfl_xor(s4, 16, 64); s4 += __shfl_xor(s4, 32, 64);
        s5 += __shfl_xor(s5, 16, 64); s5 += __shfl_xor(s5, 32, 64);
        s6 += __shfl_xor(s6, 16, 64); s6 += __shfl_xor(s6, 32, 64);
        s7 += __shfl_xor(s7, 16, 64); s7 += __shfl_xor(s7, 32, 64);
        if (lane < 16) {
            const int colloc = wn * 64 + ni * 16 + lane;
            float* dst = pc +
                ((size_t)(blockIdx.x * 2 + wm) * 128 + colloc) * 8;
            float4 p0 = {s0 * om, s1 * om, s2 * om, s3 * om};
            float4 p1 = {s4 * om, s5 * om, s6 * om, s7 * om};
            *(float4*)(dst) = p0;
            *(float4*)(dst + 4) = p1;
        }
    }
}

// ---------------------------------------------------------------------------
// Kernel C: gather 64 slices per row, combine ratios, global mean.
// ---------------------------------------------------------------------------
__global__ void finalize_sym_kernel(const float* __restrict__ pr,
                                    const float* __restrict__ pc,
                                    float* __restrict__ out, int N, int nbx) {
    const int tid = threadIdx.x;
    const int rloc16 = tid >> 4;
    const int st = tid & 15;
    const int i = blockIdx.x * 16 + rloc16;
    const int B = i >> 7;
    const int rl = i & 127;
    const int nrow = (nbx - B) * 2;

    float a0 = 0.f, a1 = 0.f, a2 = 0.f, a3 = 0.f;
    float a4 = 0.f, a5 = 0.f, a6 = 0.f, a7 = 0.f;
#pragma unroll
    for (int s4i = 0; s4i < 4; ++s4i) {
        const int sidx = st * 4 + s4i;
        const float* base;
        if (sidx < nrow) {
            const int bxx = B + (sidx >> 1);
            const int t = bxx * (bxx + 1) / 2 + B;
            base = pr + ((size_t)(t * 2 + (sidx & 1)) * 128 + rl) * 8;
        } else {
            const int m = sidx - nrow;
            const int t = B * (B + 1) / 2 + (m >> 1);
            base = pc + ((size_t)(t * 2 + (m & 1)) * 128 + rl) * 8;
        }
        float4 u0 = *(const float4*)(base);
        float4 u1 = *(const float4*)(base + 4);
        a0 += u0.x; a1 += u0.y; a2 += u0.z; a3 += u0.w;
        a4 += u1.x; a5 += u1.y; a6 += u1.z; a7 += u1.w;
    }
#pragma unroll
    for (int off = 1; off < 16; off <<= 1) {
        a0 += __shfl_xor(a0, off, 64);
        a1 += __shfl_xor(a1, off, 64);
        a2 += __shfl_xor(a2, off, 64);
        a3 += __shfl_xor(a3, off, 64);
        a4 += __shfl_xor(a4, off, 64);
        a5 += __shfl_xor(a5, off, 64);
        a6 += __shfl_xor(a6, off, 64);
        a7 += __shfl_xor(a7, off, 64);
    }
    __shared__ float lred[16];
    if (st == 0) {
        const float l = a0 / (a1 + EPSV) + a2 / (a3 + EPSV)
            + (C1E * fmaf(2.4f, a5, -a4)) / (C1E * a5 + EPSV)
            + (C2E * fmaf(2.2f, a7, -a6)) / (C2E * a7 + EPSV);
        lred[rloc16] = l;
    }
    __syncthreads();
    if (tid == 0) {
        float tot = 0.f;
#pragma unroll
        for (int k2 = 0; k2 < 16; ++k2) tot += lred[k2];
        atomicAdd(out, tot / (float)N);
    }
}

// ---------------------------------------------------------------------------
// Fallback path (144 KB ws): fp32 tile GEMM + atomic epilogue (R1, known-good)
// ---------------------------------------------------------------------------
__launch_bounds__(THREADS, 2)
__global__ void dist_loss_kernel(const float* __restrict__ x,
                                 const int* __restrict__ targets,
                                 const int* __restrict__ sub,
                                 const float* __restrict__ inv_norm,
                                 float* __restrict__ acc,
                                 int N, int D) {
    __shared__ float Asf[16][128];
    __shared__ float Bsf[16][128];

    const int nbx = N / 128;
    const int bx = blockIdx.x % nbx;
    const int by = blockIdx.x / nbx;
    const int tid = threadIdx.x;
    const int tx = tid & 15;
    const int ty = tid >> 4;
    const int rowA0 = by * 128;
    const int colB0 = bx * 128;
    const float* Abase = x + (size_t)rowA0 * D;
    const float* Bbase = x + (size_t)colB0 * D;

    float accv[8][8];
#pragma unroll
    for (int r = 0; r < 8; ++r)
#pragma unroll
        for (int c = 0; c < 8; ++c) accv[r][c] = 0.f;

    for (int kb = 0; kb < D; kb += 16) {
#pragma unroll
        for (int l = 0; l < 2; ++l) {
            const int f = tid + l * THREADS;
            const int row = f >> 2;
            const int kq = (f & 3) << 2;
            float4 va = *(const float4*)(Abase + (size_t)row * D + kb + kq);
            float4 vb = *(const float4*)(Bbase + (size_t)row * D + kb + kq);
            Asf[kq + 0][row] = va.x; Asf[kq + 1][row] = va.y;
            Asf[kq + 2][row] = va.z; Asf[kq + 3][row] = va.w;
            Bsf[kq + 0][row] = vb.x; Bsf[kq + 1][row] = vb.y;
            Bsf[kq + 2][row] = vb.z; Bsf[kq + 3][row] = vb.w;
        }
        __syncthreads();
#pragma unroll
        for (int k = 0; k < 16; ++k) {
            float4 a0 = *(const float4*)&Asf[k][ty * 8];
            float4 a1 = *(const float4*)&Asf[k][ty * 8 + 4];
            float4 b0 = *(const float4*)&Bsf[k][tx * 8];
            float4 b1 = *(const float4*)&Bsf[k][tx * 8 + 4];
            float ar[8] = {a0.x, a0.y, a0.z, a0.w, a1.x, a1.y, a1.z, a1.w};
            float br[8] = {b0.x, b0.y, b0.z, b0.w, b1.x, b1.y, b1.z, b1.w};
#pragma unroll
            for (int r = 0; r < 8; ++r)
#pragma unroll
                for (int c = 0; c < 8; ++c)
                    accv[r][c] = fmaf(ar[r], br[c], accv[r][c]);
        }
        __syncthreads();
    }

    const int row_base = rowA0 + ty * 8;
    const int col_base = colB0 + tx * 8;
    int tjc[8], sjc[8];
    float invj[8];
#pragma unroll
    for (int c = 0; c < 8; ++c) {
        tjc[c] = targets[col_base + c];
        sjc[c] = sub[col_base + c];
        invj[c] = inv_norm[col_base + c];
    }
#pragma unroll
    for (int r = 0; r < 8; ++r) {
        const int gi = row_base + r;
        const int ti = targets[gi];
        const int si = sub[gi];
        const float invi = inv_norm[gi];
        float s0 = 0.f, s1 = 0.f, s2 = 0.f, s3 = 0.f;
        float s4 = 0.f, s5 = 0.f, s6 = 0.f, s7 = 0.f;
#pragma unroll
        for (int c = 0; c < 8; ++c) {
            const int gj = col_base + c;
            const float dot = accv[r][c] * invi * invj[c];
            const float dd = sqrtf(fmaxf(2.f - 2.f * dot, 1e-12f));
            const bool same = (ti == tjc[c]);
            const bool intra = (si == sjc[c]);
            const bool pos = same && (gi != gj);
            const bool neg = !same;
            const float df = (intra ? 2.4f : 2.2f) - dd;
            const float wgt = __expf(df);
            const float v = fmaxf(dd - (intra ? 1.4f : 0.7f), 0.f);
            if (pos && intra)  { s0 += v; s1 += 1.f; }
            if (pos && !intra) { s2 += v; s3 += 1.f; }
            if (neg && intra)  { s4 += df * wgt; s5 += wgt; }
            if (neg && !intra) { s6 += df * wgt; s7 += wgt; }
        }
#pragma unroll
        for (int off = 1; off < 16; off <<= 1) {
            s0 += __shfl_xor(s0, off, 64);
            s1 += __shfl_xor(s1, off, 64);
            s2 += __shfl_xor(s2, off, 64);
            s3 += __shfl_xor(s3, off, 64);
            s4 += __shfl_xor(s4, off, 64);
            s5 += __shfl_xor(s5, off, 64);
            s6 += __shfl_xor(s6, off, 64);
            s7 += __shfl_xor(s7, off, 64);
        }
        if (tx == 0) {
            float* a = acc + (size_t)gi * 8;
            atomicAdd(a + 0, s0); atomicAdd(a + 1, s1);
            atomicAdd(a + 2, s2); atomicAdd(a + 3, s3);
            atomicAdd(a + 4, s4); atomicAdd(a + 5, s5);
            atomicAdd(a + 6, s6); atomicAdd(a + 7, s7);
        }
    }
}

__global__ void finalize_kernel(const float* __restrict__ acc,
                                float* __restrict__ out, int N) {
    float s = 0.f;
    for (int i = threadIdx.x; i < N; i += THREADS) {
        const float* a = acc + (size_t)i * 8;
        s += a[0] / (a[1] + EPSV) + a[2] / (a[3] + EPSV)
           + a[4] / (a[5] + EPSV) + a[6] / (a[7] + EPSV);
    }
#pragma unroll
    for (int off = 32; off > 0; off >>= 1) s += __shfl_down(s, off, 64);
    __shared__ float red[THREADS / 64];
    if ((threadIdx.x & 63) == 0) red[threadIdx.x >> 6] = s;
    __syncthreads();
    if (threadIdx.x == 0) {
        float tot = 0.f;
#pragma unroll
        for (int w = 0; w < THREADS / 64; ++w) tot += red[w];
        out[0] = tot / (float)N;
    }
}

// ---------------------------------------------------------------------------
extern "C" void kernel_launch(void* const* d_in, const int* in_sizes, int n_in,
                              void* d_out, int out_size, void* d_ws, size_t ws_size,
                              hipStream_t stream) {
    const float* x = (const float*)d_in[0];
    const int* targets = (const int*)d_in[1];
    const int* sub = (const int*)d_in[2];
    const int N = in_sizes[1];
    const int D = in_sizes[0] / N;

    const int nbx = N / BM;
    const int T = nbx * (nbx + 1) / 2;
    const size_t sliceB = (size_t)T * 2 * 128 * 8 * sizeof(float);
    const size_t need = (size_t)N * D * 2 + 2 * sliceB;

    if (ws_size >= need) {
        unsigned short* xb = (unsigned short*)d_ws;           // N*D bf16
        float* pr = (float*)((char*)d_ws + (size_t)N * D * 2);
        float* pc = pr + (size_t)T * 2 * 128 * 8;

        hipMemsetAsync(d_out, 0, sizeof(float), stream);
        norm_conv_kernel<<<N, THREADS, 0, stream>>>(x, xb, D);
        gram_sym_kernel<<<T, GT, 0, stream>>>(xb, targets, sub, pr, pc, D);
        finalize_sym_kernel<<<N / 16, THREADS, 0, stream>>>(
            pr, pc, (float*)d_out, N, nbx);
    } else {
        // Fallback (144 KB ws): fp32 path, known-good from round 1.
        float* inv_norm = (float*)d_ws;
        float* acc = inv_norm + N;
        hipMemsetAsync(acc, 0, (size_t)N * 8 * sizeof(float), stream);
        row_inv_norm_kernel<<<N, THREADS, 0, stream>>>(x, inv_norm, D);
        dist_loss_kernel<<<nbx * nbx, THREADS, 0, stream>>>(
            x, targets, sub, inv_norm, acc, N, D);
        finalize_kernel<<<1, THREADS, 0, stream>>>(acc, (float*)d_out, N);
    }
}

// Round 14
// 219.507 us; speedup vs baseline: 1.0795x; 1.0051x over previous
//
#include <hip/hip_runtime.h>
#include <math.h>

#define THREADS 256
#define GT 512                    // strip kernel: 8 waves
#define BM 128
#define BK 32
#define EPSV 1e-5f
#define C1E 11.023176380641601f   // e^2.4
#define C2E 9.025013499434122f    // e^2.2

typedef short bf16x8 __attribute__((ext_vector_type(8)));   // 8 bf16 = 16 B
typedef float f32x4 __attribute__((ext_vector_type(4)));

// RNE float -> bf16 bit pattern
__device__ __forceinline__ unsigned short f2bf(float f) {
    unsigned int u = __float_as_uint(f);
    u += 0x7FFFu + ((u >> 16) & 1u);
    return (unsigned short)(u >> 16);
}

#define GLDS16(g, l)                                                          \
    __builtin_amdgcn_global_load_lds(                                         \
        (const __attribute__((address_space(1))) unsigned int*)(g),           \
        (__attribute__((address_space(3))) unsigned int*)(l), 16, 0, 0)

// ---------------------------------------------------------------------------
// Kernel A (sym path): NORMALIZE + convert. xb[row] = bf16(x[row]/||x[row]||).
// ---------------------------------------------------------------------------
__launch_bounds__(THREADS)
__global__ void norm_conv_kernel(const float* __restrict__ x,
                                 unsigned short* __restrict__ xb, int D) {
    const int row = blockIdx.x;
    const float4* x4 = (const float4*)(x + (size_t)row * D);
    const int tid = threadIdx.x;

    float s = 0.f;
    for (int b = tid * 2; b * 4 < D; b += THREADS * 2) {
        float4 v0 = x4[b];
        float4 v1 = x4[b + 1];
        s += v0.x * v0.x + v0.y * v0.y + v0.z * v0.z + v0.w * v0.w
           + v1.x * v1.x + v1.y * v1.y + v1.z * v1.z + v1.w * v1.w;
    }
#pragma unroll
    for (int off = 32; off > 0; off >>= 1) s += __shfl_down(s, off, 64);
    __shared__ float red[THREADS / 64 + 1];
    if ((tid & 63) == 0) red[tid >> 6] = s;
    __syncthreads();
    if (tid == 0) {
        float tot = 0.f;
#pragma unroll
        for (int w = 0; w < THREADS / 64; ++w) tot += red[w];
        red[THREADS / 64] = 1.0f / fmaxf(sqrtf(tot), 1e-12f);
    }
    __syncthreads();
    const float inv = red[THREADS / 64];

    bf16x8* out8 = (bf16x8*)(xb + (size_t)row * D);
    for (int b = tid * 2; b * 4 < D; b += THREADS * 2) {
        float4 v0 = x4[b];
        float4 v1 = x4[b + 1];
        bf16x8 o;
        o[0] = (short)f2bf(v0.x * inv); o[1] = (short)f2bf(v0.y * inv);
        o[2] = (short)f2bf(v0.z * inv); o[3] = (short)f2bf(v0.w * inv);
        o[4] = (short)f2bf(v1.x * inv); o[5] = (short)f2bf(v1.y * inv);
        o[6] = (short)f2bf(v1.z * inv); o[7] = (short)f2bf(v1.w * inv);
        out8[b >> 1] = o;
    }
}

// Plain inv-norm (fallback path).
__global__ void row_inv_norm_kernel(const float* __restrict__ x,
                                    float* __restrict__ inv_norm, int D) {
    const int row = blockIdx.x;
    const float4* x4 = (const float4*)(x + (size_t)row * D);
    const int nf4 = D >> 2;
    float s = 0.f;
    for (int i = threadIdx.x; i < nf4; i += THREADS) {
        float4 v = x4[i];
        s += v.x * v.x + v.y * v.y + v.z * v.z + v.w * v.w;
    }
#pragma unroll
    for (int off = 32; off > 0; off >>= 1) s += __shfl_down(s, off, 64);
    __shared__ float red[THREADS / 64];
    if ((threadIdx.x & 63) == 0) red[threadIdx.x >> 6] = s;
    __syncthreads();
    if (threadIdx.x == 0) {
        float tot = 0.f;
#pragma unroll
        for (int w = 0; w < THREADS / 64; ++w) tot += red[w];
        inv_norm[row] = 1.0f / fmaxf(sqrtf(tot), 1e-12f);
    }
}

// ---------------------------------------------------------------------------
// Kernel B: STRIP-MINED symmetric bf16 Gram. Each block = 128x256 strip
// (two adjacent triangle tiles bx, bx+1 in row by). 8 waves, wave (wm,wn) =
// 64x64 quadrant; same per-wave MFMA/acc as R8. Staging per iter: A 8KB +
// B 16KB = 24KB vs 32KB for two R8 blocks -> total 528->410 MB. Theory:
// gram time == staged bytes / ~4.4 TB/s (R8/R10/R11 all ~120us at 528 MB),
// so fewer bytes is the only lever that moved.
// pr/pc tile-slice layout identical to R11; finalize unchanged.
// ---------------------------------------------------------------------------
__launch_bounds__(GT, 2)   // 16 waves/CU, VGPR cap 128 (R13-verified no spill)
__global__ void gram_strip_kernel(const unsigned short* __restrict__ xb,
                                  const int* __restrict__ targets,
                                  const int* __restrict__ sub,
                                  float* __restrict__ pr,
                                  float* __restrict__ pc,
                                  int D, int N, int nbx) {
    __shared__ unsigned short As[BM * BK];        // 8 KB
    __shared__ unsigned short Bs[2 * BM * BK];    // 16 KB (256 rows)

    // Decode strip id -> (by, s): row by has ceil((nbx-by)/2) strips.
    int sid = blockIdx.x;
    int by = 0;
    for (;;) {
        const int rowlen = (nbx - by + 1) >> 1;
        if (sid < rowlen) break;
        sid -= rowlen;
        ++by;
    }
    const int bxL = by + 2 * sid;           // left tile col-block
    const bool rv = (bxL + 1) < nbx;        // right tile valid?

    const int tid = threadIdx.x;
    const int w = tid >> 6;          // wave 0..7
    const int lane = tid & 63;
    const int wm = w & 1;            // row half (64 rows)
    const int wn = w >> 1;           // col quarter (64 of 256 cols)
    const int quad = lane >> 4;
    const int cl = lane & 15;

    const int rowA0 = by * BM;
    const int colB0 = bxL * BM;
    const unsigned short* Abase = xb + (size_t)rowA0 * D;

    // A staging: 512 chunks of 16B; thread covers chunk tid (1 glds).
    const int rA = tid >> 2, qA = (tid & 3) ^ ((rA >> 1) & 3);
    const unsigned short* sA = Abase + (size_t)rA * D + qA * 8;
    unsigned short* dA = As + (w * 64) * 8;       // wave-uniform base

    // B staging: 1024 chunks; thread covers chunks tid and tid+512.
    const int rB0 = tid >> 2, qB0 = (tid & 3) ^ ((rB0 >> 1) & 3);
    const int c1 = tid + 512;
    const int rB1 = c1 >> 2, qB1 = (c1 & 3) ^ ((rB1 >> 1) & 3);
    const int gB0 = min(colB0 + rB0, N - 1);      // clamp invalid right tile
    const int gB1 = min(colB0 + rB1, N - 1);
    const unsigned short* sB0 = xb + (size_t)gB0 * D + qB0 * 8;
    const unsigned short* sB1 = xb + (size_t)gB1 * D + qB1 * 8;
    unsigned short* dB0 = Bs + (w * 64) * 8;
    unsigned short* dB1 = Bs + (512 + w * 64) * 8;

    f32x4 accv[4][4];
#pragma unroll
    for (int i = 0; i < 4; ++i)
#pragma unroll
        for (int j = 0; j < 4; ++j) accv[i][j] = (f32x4)(0.f);

    // Fragment offsets: A rows wm*64.., B rows (cols) wn*64.. of 256.
    int aoff[4], boff[4];
#pragma unroll
    for (int f = 0; f < 4; ++f) {
        const int ar = wm * 64 + f * 16 + cl;
        aoff[f] = ar * BK + (quad ^ ((ar >> 1) & 3)) * 8;
        const int br = wn * 64 + f * 16 + cl;
        boff[f] = br * BK + (quad ^ ((br >> 1) & 3)) * 8;
    }

    for (int kb = 0; kb < D; kb += BK) {
        GLDS16(sA + kb, dA);
        GLDS16(sB0 + kb, dB0);
        GLDS16(sB1 + kb, dB1);
        __syncthreads();   // drains vmcnt: strip tiles in LDS

        bf16x8 af[4], bfv[4];
#pragma unroll
        for (int f = 0; f < 4; ++f) {
            af[f] = *(const bf16x8*)&As[aoff[f]];
            bfv[f] = *(const bf16x8*)&Bs[boff[f]];
        }
#pragma unroll
        for (int mi = 0; mi < 4; ++mi)
#pragma unroll
            for (int ni = 0; ni < 4; ++ni)
                accv[mi][ni] = __builtin_amdgcn_mfma_f32_16x16x32_bf16(
                    af[mi], bfv[ni], accv[mi][ni], 0, 0, 0);
        __syncthreads();   // tiles consumed
    }

    // Which tile does this wave's col-quarter belong to?
    const int tq = bxL + (wn >> 1);          // tile col-block
    const bool tval = (wn < 2) || rv;        // quarter's tile valid
    const int wnp = wn & 1;                  // tile-local col half
    const int tkq = tq * (tq + 1) / 2 + by;  // tile triangle index

    // ---------------- epilogue pass 1: dd + row partials ----------------
    int tj[4], sj[4];
#pragma unroll
    for (int ni = 0; ni < 4; ++ni) {
        const int gc = min(colB0 + wn * 64 + ni * 16 + cl, N - 1);
        tj[ni] = targets[gc];
        sj[ni] = sub[gc];
    }

#pragma unroll
    for (int mi = 0; mi < 4; ++mi) {
#pragma unroll
        for (int r = 0; r < 4; ++r) {
            const int gi = rowA0 + wm * 64 + mi * 16 + quad * 4 + r;
            const int ti = targets[gi];
            const int si = sub[gi];

            float s0 = 0.f, s1 = 0.f, s2 = 0.f, s3 = 0.f;
            float s4 = 0.f, s5 = 0.f, s6 = 0.f, s7 = 0.f;
#pragma unroll
            for (int ni = 0; ni < 4; ++ni) {
                const int gj = colB0 + wn * 64 + ni * 16 + cl;
                const float d2 = fmaf(-2.f, accv[mi][ni][r], 2.f);
                const float dd = sqrtf(fmaxf(d2, 1e-12f));
                accv[mi][ni][r] = dd;          // overwrite: pass 2 reuses
                const bool same = (ti == tj[ni]);
                const bool intra = (si == sj[ni]);
                const bool pos = same && (gi != gj);
                const bool neg = !same;
                const float mg = intra ? 1.4f : 0.7f;
                const float v = fmaxf(dd - mg, 0.f);
                const float e = __expf(-dd);   // e^alpha folded in finalize
                const float de = dd * e;
                if (pos && intra)  { s0 += v;  s1 += 1.f; }
                if (pos && !intra) { s2 += v;  s3 += 1.f; }
                if (neg && intra)  { s4 += de; s5 += e; }
                if (neg && !intra) { s6 += de; s7 += e; }
            }
#pragma unroll
            for (int off = 1; off < 16; off <<= 1) {
                s0 += __shfl_xor(s0, off, 64);
                s1 += __shfl_xor(s1, off, 64);
                s2 += __shfl_xor(s2, off, 64);
                s3 += __shfl_xor(s3, off, 64);
                s4 += __shfl_xor(s4, off, 64);
                s5 += __shfl_xor(s5, off, 64);
                s6 += __shfl_xor(s6, off, 64);
                s7 += __shfl_xor(s7, off, 64);
            }
            if (cl == 0 && tval) {
                const int rloc = wm * 64 + mi * 16 + quad * 4 + r;
                float* dst = pr + ((size_t)(tkq * 2 + wnp) * 128 + rloc) * 8;
                float4 p0 = {s0, s1, s2, s3};
                float4 p1 = {s4, s5, s6, s7};
                *(float4*)(dst) = p0;
                *(float4*)(dst + 4) = p1;
            }
        }
    }

    // ---------------- epilogue pass 2: col partials ----------------
    const float om = (tq == by) ? 0.f : 1.f;   // diagonal tile: zero col side
#pragma unroll
    for (int ni = 0; ni < 4; ++ni) {
        const int gj = colB0 + wn * 64 + ni * 16 + cl;
        const int tjc = tj[ni];
        const int sjc = sj[ni];
        float s0 = 0.f, s1 = 0.f, s2 = 0.f, s3 = 0.f;
        float s4 = 0.f, s5 = 0.f, s6 = 0.f, s7 = 0.f;
#pragma unroll
        for (int mi = 0; mi < 4; ++mi) {
#pragma unroll
            for (int r = 0; r < 4; ++r) {
                const int gi = rowA0 + wm * 64 + mi * 16 + quad * 4 + r;
                const int ti = targets[gi];     // L1-hot reload
                const int si = sub[gi];
                const float dd = accv[mi][ni][r];
                const bool same = (ti == tjc);
                const bool intra = (si == sjc);
                const bool pos = same && (gi != gj);
                const bool neg = !same;
                const float mg = intra ? 1.4f : 0.7f;
                const float v = fmaxf(dd - mg, 0.f);
                const float e = __expf(-dd);
                const float de = dd * e;
                if (pos && intra)  { s0 += v;  s1 += 1.f; }
                if (pos && !intra) { s2 += v;  s3 += 1.f; }
                if (neg && intra)  { s4 += de; s5 += e; }
                if (neg && !intra) { s6 += de; s7 += e; }
            }
        }
        s0 += __shfl_xor(s0, 16, 64); s0 += __shfl_xor(s0, 32, 64);
        s1 += __shfl_xor(s1, 16, 64); s1 += __shfl_xor(s1, 32, 64);
        s2 += __shfl_xor(s2, 16, 64); s2 += __shfl_xor(s2, 32, 64);
        s3 += __shfl_xor(s3, 16, 64); s3 += __shfl_xor(s3, 32, 64);
        s4 += __shfl_xor(s4, 16, 64); s4 += __shfl_xor(s4, 32, 64);
        s5 += __shfl_xor(s5, 16, 64); s5 += __shfl_xor(s5, 32, 64);
        s6 += __shfl_xor(s6, 16, 64); s6 += __shfl_xor(s6, 32, 64);
        s7 += __shfl_xor(s7, 16, 64); s7 += __shfl_xor(s7, 32, 64);
        if (lane < 16 && tval) {
            const int colloc = wnp * 64 + ni * 16 + lane;
            float* dst = pc + ((size_t)(tkq * 2 + wm) * 128 + colloc) * 8;
            float4 p0 = {s0 * om, s1 * om, s2 * om, s3 * om};
            float4 p1 = {s4 * om, s5 * om, s6 * om, s7 * om};
            *(float4*)(dst) = p0;
            *(float4*)(dst + 4) = p1;
        }
    }
}

// ---------------------------------------------------------------------------
// Kernel C: gather 64 slices per row, combine ratios, global mean.
// (Identical to R11 — pr/pc layout unchanged.)
// ---------------------------------------------------------------------------
__global__ void finalize_sym_kernel(const float* __restrict__ pr,
                                    const float* __restrict__ pc,
                                    float* __restrict__ out, int N, int nbx) {
    const int tid = threadIdx.x;
    const int rloc16 = tid >> 4;
    const int st = tid & 15;
    const int i = blockIdx.x * 16 + rloc16;
    const int B = i >> 7;
    const int rl = i & 127;
    const int nrow = (nbx - B) * 2;

    float a0 = 0.f, a1 = 0.f, a2 = 0.f, a3 = 0.f;
    float a4 = 0.f, a5 = 0.f, a6 = 0.f, a7 = 0.f;
#pragma unroll
    for (int s4i = 0; s4i < 4; ++s4i) {
        const int sidx = st * 4 + s4i;
        const float* base;
        if (sidx < nrow) {
            const int bxx = B + (sidx >> 1);
            const int t = bxx * (bxx + 1) / 2 + B;
            base = pr + ((size_t)(t * 2 + (sidx & 1)) * 128 + rl) * 8;
        } else {
            const int m = sidx - nrow;
            const int t = B * (B + 1) / 2 + (m >> 1);
            base = pc + ((size_t)(t * 2 + (m & 1)) * 128 + rl) * 8;
        }
        float4 u0 = *(const float4*)(base);
        float4 u1 = *(const float4*)(base + 4);
        a0 += u0.x; a1 += u0.y; a2 += u0.z; a3 += u0.w;
        a4 += u1.x; a5 += u1.y; a6 += u1.z; a7 += u1.w;
    }
#pragma unroll
    for (int off = 1; off < 16; off <<= 1) {
        a0 += __shfl_xor(a0, off, 64);
        a1 += __shfl_xor(a1, off, 64);
        a2 += __shfl_xor(a2, off, 64);
        a3 += __shfl_xor(a3, off, 64);
        a4 += __shfl_xor(a4, off, 64);
        a5 += __shfl_xor(a5, off, 64);
        a6 += __shfl_xor(a6, off, 64);
        a7 += __shfl_xor(a7, off, 64);
    }
    __shared__ float lred[16];
    if (st == 0) {
        const float l = a0 / (a1 + EPSV) + a2 / (a3 + EPSV)
            + (C1E * fmaf(2.4f, a5, -a4)) / (C1E * a5 + EPSV)
            + (C2E * fmaf(2.2f, a7, -a6)) / (C2E * a7 + EPSV);
        lred[rloc16] = l;
    }
    __syncthreads();
    if (tid == 0) {
        float tot = 0.f;
#pragma unroll
        for (int k2 = 0; k2 < 16; ++k2) tot += lred[k2];
        atomicAdd(out, tot / (float)N);
    }
}

// ---------------------------------------------------------------------------
// Fallback path (144 KB ws): fp32 tile GEMM + atomic epilogue (R1, known-good)
// ---------------------------------------------------------------------------
__launch_bounds__(THREADS, 2)
__global__ void dist_loss_kernel(const float* __restrict__ x,
                                 const int* __restrict__ targets,
                                 const int* __restrict__ sub,
                                 const float* __restrict__ inv_norm,
                                 float* __restrict__ acc,
                                 int N, int D) {
    __shared__ float Asf[16][128];
    __shared__ float Bsf[16][128];

    const int nbx = N / 128;
    const int bx = blockIdx.x % nbx;
    const int by = blockIdx.x / nbx;
    const int tid = threadIdx.x;
    const int tx = tid & 15;
    const int ty = tid >> 4;
    const int rowA0 = by * 128;
    const int colB0 = bx * 128;
    const float* Abase = x + (size_t)rowA0 * D;
    const float* Bbase = x + (size_t)colB0 * D;

    float accv[8][8];
#pragma unroll
    for (int r = 0; r < 8; ++r)
#pragma unroll
        for (int c = 0; c < 8; ++c) accv[r][c] = 0.f;

    for (int kb = 0; kb < D; kb += 16) {
#pragma unroll
        for (int l = 0; l < 2; ++l) {
            const int f = tid + l * THREADS;
            const int row = f >> 2;
            const int kq = (f & 3) << 2;
            float4 va = *(const float4*)(Abase + (size_t)row * D + kb + kq);
            float4 vb = *(const float4*)(Bbase + (size_t)row * D + kb + kq);
            Asf[kq + 0][row] = va.x; Asf[kq + 1][row] = va.y;
            Asf[kq + 2][row] = va.z; Asf[kq + 3][row] = va.w;
            Bsf[kq + 0][row] = vb.x; Bsf[kq + 1][row] = vb.y;
            Bsf[kq + 2][row] = vb.z; Bsf[kq + 3][row] = vb.w;
        }
        __syncthreads();
#pragma unroll
        for (int k = 0; k < 16; ++k) {
            float4 a0 = *(const float4*)&Asf[k][ty * 8];
            float4 a1 = *(const float4*)&Asf[k][ty * 8 + 4];
            float4 b0 = *(const float4*)&Bsf[k][tx * 8];
            float4 b1 = *(const float4*)&Bsf[k][tx * 8 + 4];
            float ar[8] = {a0.x, a0.y, a0.z, a0.w, a1.x, a1.y, a1.z, a1.w};
            float br[8] = {b0.x, b0.y, b0.z, b0.w, b1.x, b1.y, b1.z, b1.w};
#pragma unroll
            for (int r = 0; r < 8; ++r)
#pragma unroll
                for (int c = 0; c < 8; ++c)
                    accv[r][c] = fmaf(ar[r], br[c], accv[r][c]);
        }
        __syncthreads();
    }

    const int row_base = rowA0 + ty * 8;
    const int col_base = colB0 + tx * 8;
    int tjc[8], sjc[8];
    float invj[8];
#pragma unroll
    for (int c = 0; c < 8; ++c) {
        tjc[c] = targets[col_base + c];
        sjc[c] = sub[col_base + c];
        invj[c] = inv_norm[col_base + c];
    }
#pragma unroll
    for (int r = 0; r < 8; ++r) {
        const int gi = row_base + r;
        const int ti = targets[gi];
        const int si = sub[gi];
        const float invi = inv_norm[gi];
        float s0 = 0.f, s1 = 0.f, s2 = 0.f, s3 = 0.f;
        float s4 = 0.f, s5 = 0.f, s6 = 0.f, s7 = 0.f;
#pragma unroll
        for (int c = 0; c < 8; ++c) {
            const int gj = col_base + c;
            const float dot = accv[r][c] * invi * invj[c];
            const float dd = sqrtf(fmaxf(2.f - 2.f * dot, 1e-12f));
            const bool same = (ti == tjc[c]);
            const bool intra = (si == sjc[c]);
            const bool pos = same && (gi != gj);
            const bool neg = !same;
            const float df = (intra ? 2.4f : 2.2f) - dd;
            const float wgt = __expf(df);
            const float v = fmaxf(dd - (intra ? 1.4f : 0.7f), 0.f);
            if (pos && intra)  { s0 += v; s1 += 1.f; }
            if (pos && !intra) { s2 += v; s3 += 1.f; }
            if (neg && intra)  { s4 += df * wgt; s5 += wgt; }
            if (neg && !intra) { s6 += df * wgt; s7 += wgt; }
        }
#pragma unroll
        for (int off = 1; off < 16; off <<= 1) {
            s0 += __shfl_xor(s0, off, 64);
            s1 += __shfl_xor(s1, off, 64);
            s2 += __shfl_xor(s2, off, 64);
            s3 += __shfl_xor(s3, off, 64);
            s4 += __shfl_xor(s4, off, 64);
            s5 += __shfl_xor(s5, off, 64);
            s6 += __shfl_xor(s6, off, 64);
            s7 += __shfl_xor(s7, off, 64);
        }
        if (tx == 0) {
            float* a = acc + (size_t)gi * 8;
            atomicAdd(a + 0, s0); atomicAdd(a + 1, s1);
            atomicAdd(a + 2, s2); atomicAdd(a + 3, s3);
            atomicAdd(a + 4, s4); atomicAdd(a + 5, s5);
            atomicAdd(a + 6, s6); atomicAdd(a + 7, s7);
        }
    }
}

__global__ void finalize_kernel(const float* __restrict__ acc,
                                float* __restrict__ out, int N) {
    float s = 0.f;
    for (int i = threadIdx.x; i < N; i += THREADS) {
        const float* a = acc + (size_t)i * 8;
        s += a[0] / (a[1] + EPSV) + a[2] / (a[3] + EPSV)
           + a[4] / (a[5] + EPSV) + a[6] / (a[7] + EPSV);
    }
#pragma unroll
    for (int off = 32; off > 0; off >>= 1) s += __shfl_down(s, off, 64);
    __shared__ float red[THREADS / 64];
    if ((threadIdx.x & 63) == 0) red[threadIdx.x >> 6] = s;
    __syncthreads();
    if (threadIdx.x == 0) {
        float tot = 0.f;
#pragma unroll
        for (int w = 0; w < THREADS / 64; ++w) tot += red[w];
        out[0] = tot / (float)N;
    }
}

// ---------------------------------------------------------------------------
extern "C" void kernel_launch(void* const* d_in, const int* in_sizes, int n_in,
                              void* d_out, int out_size, void* d_ws, size_t ws_size,
                              hipStream_t stream) {
    const float* x = (const float*)d_in[0];
    const int* targets = (const int*)d_in[1];
    const int* sub = (const int*)d_in[2];
    const int N = in_sizes[1];
    const int D = in_sizes[0] / N;

    const int nbx = N / BM;
    const int T = nbx * (nbx + 1) / 2;
    const size_t sliceB = (size_t)T * 2 * 128 * 8 * sizeof(float);
    const size_t need = (size_t)N * D * 2 + 2 * sliceB;

    if (ws_size >= need) {
        unsigned short* xb = (unsigned short*)d_ws;           // N*D bf16
        float* pr = (float*)((char*)d_ws + (size_t)N * D * 2);
        float* pc = pr + (size_t)T * 2 * 128 * 8;

        int strips = 0;
        for (int by = 0; by < nbx; ++by) strips += (nbx - by + 1) >> 1;

        hipMemsetAsync(d_out, 0, sizeof(float), stream);
        norm_conv_kernel<<<N, THREADS, 0, stream>>>(x, xb, D);
        gram_strip_kernel<<<strips, GT, 0, stream>>>(xb, targets, sub,
                                                     pr, pc, D, N, nbx);
        finalize_sym_kernel<<<N / 16, THREADS, 0, stream>>>(
            pr, pc, (float*)d_out, N, nbx);
    } else {
        // Fallback (144 KB ws): fp32 path, known-good from round 1.
        float* inv_norm = (float*)d_ws;
        float* acc = inv_norm + N;
        hipMemsetAsync(acc, 0, (size_t)N * 8 * sizeof(float), stream);
        row_inv_norm_kernel<<<N, THREADS, 0, stream>>>(x, inv_norm, D);
        dist_loss_kernel<<<nbx * nbx, THREADS, 0, stream>>>(
            x, targets, sub, inv_norm, acc, N, D);
        finalize_kernel<<<1, THREADS, 0, stream>>>(acc, (float*)d_out, N);
    }
}

// Round 15
// 201.478 us; speedup vs baseline: 1.1761x; 1.0895x over previous
//
#include <hip/hip_runtime.h>
#include <math.h>

#define THREADS 256
#define BM 128
#define BK 32
#define EPSV 1e-5f
#define C1E 11.023176380641601f   // e^2.4
#define C2E 9.025013499434122f    // e^2.2
#define FP8_SCALE 256.0f          // power-of-2 row scale into e4m3 range
#define INV_SCALE2 1.52587890625e-5f   // 1/65536, exact

typedef float f32x4 __attribute__((ext_vector_type(4)));

// ---------------------------------------------------------------------------
// Kernel A (fp8 path): normalize row, scale by 256, convert to OCP e4m3.
// xq[row][k] = e4m3(256 * x[row][k] / ||x[row]||). Scale is exact pow2;
// epilogue divides dots by 65536. Elements land in +-28 (max ~0.11*256):
// no saturation, no denormals (min normal 2^-6 = 0.0156 << sigma 5.7).
// ---------------------------------------------------------------------------
__launch_bounds__(THREADS)
__global__ void norm_conv_fp8_kernel(const float* __restrict__ x,
                                     unsigned char* __restrict__ xq, int D) {
    const int row = blockIdx.x;
    const float4* x4 = (const float4*)(x + (size_t)row * D);
    const int tid = threadIdx.x;

    float s = 0.f;
    for (int b = tid * 2; b * 4 < D; b += THREADS * 2) {
        float4 v0 = x4[b];
        float4 v1 = x4[b + 1];
        s += v0.x * v0.x + v0.y * v0.y + v0.z * v0.z + v0.w * v0.w
           + v1.x * v1.x + v1.y * v1.y + v1.z * v1.z + v1.w * v1.w;
    }
#pragma unroll
    for (int off = 32; off > 0; off >>= 1) s += __shfl_down(s, off, 64);
    __shared__ float red[THREADS / 64 + 1];
    if ((tid & 63) == 0) red[tid >> 6] = s;
    __syncthreads();
    if (tid == 0) {
        float tot = 0.f;
#pragma unroll
        for (int w = 0; w < THREADS / 64; ++w) tot += red[w];
        red[THREADS / 64] = FP8_SCALE / fmaxf(sqrtf(tot), 1e-12f);
    }
    __syncthreads();
    const float sc = red[THREADS / 64];

    int2* out = (int2*)(xq + (size_t)row * D);
    for (int b = tid * 2; b * 4 < D; b += THREADS * 2) {
        float4 v0 = x4[b];
        float4 v1 = x4[b + 1];
        int lo = __builtin_amdgcn_cvt_pk_fp8_f32(v0.x * sc, v0.y * sc, 0, 0);
        lo = __builtin_amdgcn_cvt_pk_fp8_f32(v0.z * sc, v0.w * sc, lo, 1);
        int hi = __builtin_amdgcn_cvt_pk_fp8_f32(v1.x * sc, v1.y * sc, 0, 0);
        hi = __builtin_amdgcn_cvt_pk_fp8_f32(v1.z * sc, v1.w * sc, hi, 1);
        int2 o; o.x = lo; o.y = hi;
        out[b >> 1] = o;
    }
}

// Plain inv-norm (fallback path).
__global__ void row_inv_norm_kernel(const float* __restrict__ x,
                                    float* __restrict__ inv_norm, int D) {
    const int row = blockIdx.x;
    const float4* x4 = (const float4*)(x + (size_t)row * D);
    const int nf4 = D >> 2;
    float s = 0.f;
    for (int i = threadIdx.x; i < nf4; i += THREADS) {
        float4 v = x4[i];
        s += v.x * v.x + v.y * v.y + v.z * v.z + v.w * v.w;
    }
#pragma unroll
    for (int off = 32; off > 0; off >>= 1) s += __shfl_down(s, off, 64);
    __shared__ float red[THREADS / 64];
    if ((threadIdx.x & 63) == 0) red[threadIdx.x >> 6] = s;
    __syncthreads();
    if (threadIdx.x == 0) {
        float tot = 0.f;
#pragma unroll
        for (int w = 0; w < THREADS / 64; ++w) tot += red[w];
        inv_norm[row] = 1.0f / fmaxf(sqrtf(tot), 1e-12f);
    }
}

#define GLDS16(g, l)                                                          \
    __builtin_amdgcn_global_load_lds(                                         \
        (const __attribute__((address_space(1))) unsigned int*)(g),           \
        (__attribute__((address_space(3))) unsigned int*)(l), 16, 0, 0)

// ---------------------------------------------------------------------------
// Kernel B: SYMMETRIC fp8 Gram, EXACT R8/R11 geometry (528 tri-tiles, 256
// threads, 4 waves of 64x64, BK=32, single-buffer glds K-loop) — the proven
// best schedule (~283 block-iters/us). fp8 halves the bytes per iteration:
// tile = 4 KB/matrix (1 glds/thread each), 8 KB LDS total, staged bytes
// 528 -> 264 MB. MFMA: mfma_f32_16x16x32_fp8_fp8, A/B frag = 8 consecutive
// K bytes per lane (long), layout k = quad*8+j like bf16-16x16x32.
// Fragment ds_read_b64: each 32B row spans 8 banks, rows 0..3 cover all 32
// -> uniform, no swizzle needed. Decisive test: bytes-bound -> ~70us;
// latency-bound -> ~115us unchanged.
// vals: 0 s_pos_intra 1 cnt_pi 2 s_pos_cross 3 cnt_pc
//       4 DE_neg_intra 5 E_neg_intra 6 DE_neg_cross 7 E_neg_cross
// ---------------------------------------------------------------------------
__launch_bounds__(THREADS, 2)
__global__ void gram_fp8_kernel(const unsigned char* __restrict__ xq,
                                const int* __restrict__ targets,
                                const int* __restrict__ sub,
                                float* __restrict__ pr,
                                float* __restrict__ pc,
                                int D) {
    __shared__ unsigned char As[BM * BK];   // 4 KB
    __shared__ unsigned char Bs[BM * BK];   // 4 KB

    // Triangular decode: tk = bx*(bx+1)/2 + by, by <= bx.
    const int tk = blockIdx.x;
    int bx = (int)((sqrtf(8.0f * tk + 1.0f) - 1.0f) * 0.5f);
    while ((bx + 1) * (bx + 2) / 2 <= tk) ++bx;
    while (bx * (bx + 1) / 2 > tk) --bx;
    const int by = tk - bx * (bx + 1) / 2;

    const int tid = threadIdx.x;
    const int w = tid >> 6;          // wave 0..3
    const int lane = tid & 63;
    const int wm = w & 1;            // row-half
    const int wn = w >> 1;           // col-half
    const int quad = lane >> 4;
    const int cl = lane & 15;

    const int rowA0 = by * BM;
    const int colB0 = bx * BM;
    const unsigned char* Abase = xq + (size_t)rowA0 * D;
    const unsigned char* Bbase = xq + (size_t)colB0 * D;

    // Staging: tile = 128 rows x 32 B = 256 chunks of 16B; 1 chunk/thread
    // per matrix. chunk c=tid: row = c>>1, 16B-half q = c&1.
    const int rS = tid >> 1, qS = tid & 1;
    const unsigned char* sA = Abase + (size_t)rS * D + qS * 16;
    const unsigned char* sB = Bbase + (size_t)rS * D + qS * 16;
    unsigned char* dA = As + (w * 64) * 16;   // wave-uniform base + lane*16
    unsigned char* dB = Bs + (w * 64) * 16;

    f32x4 accv[4][4];
#pragma unroll
    for (int i = 0; i < 4; ++i)
#pragma unroll
        for (int j = 0; j < 4; ++j) accv[i][j] = (f32x4)(0.f);

    // Fragment byte offsets: row r holds K 0..31 contiguous; lane reads
    // 8 bytes at r*32 + quad*8 (b64, bank-uniform across the wave).
    int aoff[4], boff[4];
#pragma unroll
    for (int f = 0; f < 4; ++f) {
        const int ar = wm * 64 + f * 16 + cl;
        aoff[f] = ar * BK + quad * 8;
        const int br = wn * 64 + f * 16 + cl;
        boff[f] = br * BK + quad * 8;
    }

    for (int kb = 0; kb < D; kb += BK) {
        GLDS16(sA + kb, dA);
        GLDS16(sB + kb, dB);
        __syncthreads();   // drains vmcnt: tiles in LDS

        long af[4], bfv[4];
#pragma unroll
        for (int f = 0; f < 4; ++f) {
            af[f] = *(const long*)&As[aoff[f]];
            bfv[f] = *(const long*)&Bs[boff[f]];
        }
#pragma unroll
        for (int mi = 0; mi < 4; ++mi)
#pragma unroll
            for (int ni = 0; ni < 4; ++ni)
                accv[mi][ni] = __builtin_amdgcn_mfma_f32_16x16x32_fp8_fp8(
                    af[mi], bfv[ni], accv[mi][ni], 0, 0, 0);
        __syncthreads();   // tiles consumed
    }

    // ---------------- epilogue pass 1: dd + row partials ----------------
    // C/D map: col = cl, row = quad*4 + reg. Dots carry scale 65536.
    int tj[4], sj[4];
#pragma unroll
    for (int ni = 0; ni < 4; ++ni) {
        const int gc = colB0 + wn * 64 + ni * 16 + cl;
        tj[ni] = targets[gc];
        sj[ni] = sub[gc];
    }

#pragma unroll
    for (int mi = 0; mi < 4; ++mi) {
#pragma unroll
        for (int r = 0; r < 4; ++r) {
            const int gi = rowA0 + wm * 64 + mi * 16 + quad * 4 + r;
            const int ti = targets[gi];
            const int si = sub[gi];

            float s0 = 0.f, s1 = 0.f, s2 = 0.f, s3 = 0.f;
            float s4 = 0.f, s5 = 0.f, s6 = 0.f, s7 = 0.f;
#pragma unroll
            for (int ni = 0; ni < 4; ++ni) {
                const int gj = colB0 + wn * 64 + ni * 16 + cl;
                const float d2 =
                    fmaf(-2.0f * INV_SCALE2, accv[mi][ni][r], 2.0f);
                const float dd = sqrtf(fmaxf(d2, 1e-12f));
                accv[mi][ni][r] = dd;          // overwrite: pass 2 reuses
                const bool same = (ti == tj[ni]);
                const bool intra = (si == sj[ni]);
                const bool pos = same && (gi != gj);
                const bool neg = !same;
                const float mg = intra ? 1.4f : 0.7f;
                const float v = fmaxf(dd - mg, 0.f);
                const float e = __expf(-dd);   // e^alpha folded in finalize
                const float de = dd * e;
                if (pos && intra)  { s0 += v;  s1 += 1.f; }
                if (pos && !intra) { s2 += v;  s3 += 1.f; }
                if (neg && intra)  { s4 += de; s5 += e; }
                if (neg && !intra) { s6 += de; s7 += e; }
            }
#pragma unroll
            for (int off = 1; off < 16; off <<= 1) {
                s0 += __shfl_xor(s0, off, 64);
                s1 += __shfl_xor(s1, off, 64);
                s2 += __shfl_xor(s2, off, 64);
                s3 += __shfl_xor(s3, off, 64);
                s4 += __shfl_xor(s4, off, 64);
                s5 += __shfl_xor(s5, off, 64);
                s6 += __shfl_xor(s6, off, 64);
                s7 += __shfl_xor(s7, off, 64);
            }
            if (cl == 0) {
                const int rloc = wm * 64 + mi * 16 + quad * 4 + r;
                float* dst = pr +
                    ((size_t)(blockIdx.x * 2 + wn) * 128 + rloc) * 8;
                float4 p0 = {s0, s1, s2, s3};
                float4 p1 = {s4, s5, s6, s7};
                *(float4*)(dst) = p0;
                *(float4*)(dst + 4) = p1;
            }
        }
    }

    // ---------------- epilogue pass 2: col partials ----------------
    const float om = (bx == by) ? 0.f : 1.f;   // diag tiles: zero col side
#pragma unroll
    for (int ni = 0; ni < 4; ++ni) {
        const int gj = colB0 + wn * 64 + ni * 16 + cl;
        const int tjc = tj[ni];
        const int sjc = sj[ni];
        float s0 = 0.f, s1 = 0.f, s2 = 0.f, s3 = 0.f;
        float s4 = 0.f, s5 = 0.f, s6 = 0.f, s7 = 0.f;
#pragma unroll
        for (int mi = 0; mi < 4; ++mi) {
#pragma unroll
            for (int r = 0; r < 4; ++r) {
                const int gi = rowA0 + wm * 64 + mi * 16 + quad * 4 + r;
                const int ti = targets[gi];     // L1-hot reload
                const int si = sub[gi];
                const float dd = accv[mi][ni][r];
                const bool same = (ti == tjc);
                const bool intra = (si == sjc);
                const bool pos = same && (gi != gj);
                const bool neg = !same;
                const float mg = intra ? 1.4f : 0.7f;
                const float v = fmaxf(dd - mg, 0.f);
                const float e = __expf(-dd);
                const float de = dd * e;
                if (pos && intra)  { s0 += v;  s1 += 1.f; }
                if (pos && !intra) { s2 += v;  s3 += 1.f; }
                if (neg && intra)  { s4 += de; s5 += e; }
                if (neg && !intra) { s6 += de; s7 += e; }
            }
        }
        s0 += __shfl_xor(s0, 16, 64); s0 += __shfl_xor(s0, 32, 64);
        s1 += __shfl_xor(s1, 16, 64); s1 += __shfl_xor(s1, 32, 64);
        s2 += __shfl_xor(s2, 16, 64); s2 += __shfl_xor(s2, 32, 64);
        s3 += __shfl_xor(s3, 16, 64); s3 += __shfl_xor(s3, 32, 64);
        s4 += __shfl_xor(s4, 16, 64); s4 += __shfl_xor(s4, 32, 64);
        s5 += __shfl_xor(s5, 16, 64); s5 += __shfl_xor(s5, 32, 64);
        s6 += __shfl_xor(s6, 16, 64); s6 += __shfl_xor(s6, 32, 64);
        s7 += __shfl_xor(s7, 16, 64); s7 += __shfl_xor(s7, 32, 64);
        if (lane < 16) {
            const int colloc = wn * 64 + ni * 16 + lane;
            float* dst = pc +
                ((size_t)(blockIdx.x * 2 + wm) * 128 + colloc) * 8;
            float4 p0 = {s0 * om, s1 * om, s2 * om, s3 * om};
            float4 p1 = {s4 * om, s5 * om, s6 * om, s7 * om};
            *(float4*)(dst) = p0;
            *(float4*)(dst + 4) = p1;
        }
    }
}

// ---------------------------------------------------------------------------
// Kernel C: gather 64 slices per row, combine ratios, global mean.
// (Identical to R11 — pr/pc layout unchanged.)
// ---------------------------------------------------------------------------
__global__ void finalize_sym_kernel(const float* __restrict__ pr,
                                    const float* __restrict__ pc,
                                    float* __restrict__ out, int N, int nbx) {
    const int tid = threadIdx.x;
    const int rloc16 = tid >> 4;
    const int st = tid & 15;
    const int i = blockIdx.x * 16 + rloc16;
    const int B = i >> 7;
    const int rl = i & 127;
    const int nrow = (nbx - B) * 2;

    float a0 = 0.f, a1 = 0.f, a2 = 0.f, a3 = 0.f;
    float a4 = 0.f, a5 = 0.f, a6 = 0.f, a7 = 0.f;
#pragma unroll
    for (int s4i = 0; s4i < 4; ++s4i) {
        const int sidx = st * 4 + s4i;
        const float* base;
        if (sidx < nrow) {
            const int bxx = B + (sidx >> 1);
            const int t = bxx * (bxx + 1) / 2 + B;
            base = pr + ((size_t)(t * 2 + (sidx & 1)) * 128 + rl) * 8;
        } else {
            const int m = sidx - nrow;
            const int t = B * (B + 1) / 2 + (m >> 1);
            base = pc + ((size_t)(t * 2 + (m & 1)) * 128 + rl) * 8;
        }
        float4 u0 = *(const float4*)(base);
        float4 u1 = *(const float4*)(base + 4);
        a0 += u0.x; a1 += u0.y; a2 += u0.z; a3 += u0.w;
        a4 += u1.x; a5 += u1.y; a6 += u1.z; a7 += u1.w;
    }
#pragma unroll
    for (int off = 1; off < 16; off <<= 1) {
        a0 += __shfl_xor(a0, off, 64);
        a1 += __shfl_xor(a1, off, 64);
        a2 += __shfl_xor(a2, off, 64);
        a3 += __shfl_xor(a3, off, 64);
        a4 += __shfl_xor(a4, off, 64);
        a5 += __shfl_xor(a5, off, 64);
        a6 += __shfl_xor(a6, off, 64);
        a7 += __shfl_xor(a7, off, 64);
    }
    __shared__ float lred[16];
    if (st == 0) {
        const float l = a0 / (a1 + EPSV) + a2 / (a3 + EPSV)
            + (C1E * fmaf(2.4f, a5, -a4)) / (C1E * a5 + EPSV)
            + (C2E * fmaf(2.2f, a7, -a6)) / (C2E * a7 + EPSV);
        lred[rloc16] = l;
    }
    __syncthreads();
    if (tid == 0) {
        float tot = 0.f;
#pragma unroll
        for (int k2 = 0; k2 < 16; ++k2) tot += lred[k2];
        atomicAdd(out, tot / (float)N);
    }
}

// ---------------------------------------------------------------------------
// Fallback path (144 KB ws): fp32 tile GEMM + atomic epilogue (R1, known-good)
// ---------------------------------------------------------------------------
__launch_bounds__(THREADS, 2)
__global__ void dist_loss_kernel(const float* __restrict__ x,
                                 const int* __restrict__ targets,
                                 const int* __restrict__ sub,
                                 const float* __restrict__ inv_norm,
                                 float* __restrict__ acc,
                                 int N, int D) {
    __shared__ float Asf[16][128];
    __shared__ float Bsf[16][128];

    const int nbx = N / 128;
    const int bx = blockIdx.x % nbx;
    const int by = blockIdx.x / nbx;
    const int tid = threadIdx.x;
    const int tx = tid & 15;
    const int ty = tid >> 4;
    const int rowA0 = by * 128;
    const int colB0 = bx * 128;
    const float* Abase = x + (size_t)rowA0 * D;
    const float* Bbase = x + (size_t)colB0 * D;

    float accv[8][8];
#pragma unroll
    for (int r = 0; r < 8; ++r)
#pragma unroll
        for (int c = 0; c < 8; ++c) accv[r][c] = 0.f;

    for (int kb = 0; kb < D; kb += 16) {
#pragma unroll
        for (int l = 0; l < 2; ++l) {
            const int f = tid + l * THREADS;
            const int row = f >> 2;
            const int kq = (f & 3) << 2;
            float4 va = *(const float4*)(Abase + (size_t)row * D + kb + kq);
            float4 vb = *(const float4*)(Bbase + (size_t)row * D + kb + kq);
            Asf[kq + 0][row] = va.x; Asf[kq + 1][row] = va.y;
            Asf[kq + 2][row] = va.z; Asf[kq + 3][row] = va.w;
            Bsf[kq + 0][row] = vb.x; Bsf[kq + 1][row] = vb.y;
            Bsf[kq + 2][row] = vb.z; Bsf[kq + 3][row] = vb.w;
        }
        __syncthreads();
#pragma unroll
        for (int k = 0; k < 16; ++k) {
            float4 a0 = *(const float4*)&Asf[k][ty * 8];
            float4 a1 = *(const float4*)&Asf[k][ty * 8 + 4];
            float4 b0 = *(const float4*)&Bsf[k][tx * 8];
            float4 b1 = *(const float4*)&Bsf[k][tx * 8 + 4];
            float ar[8] = {a0.x, a0.y, a0.z, a0.w, a1.x, a1.y, a1.z, a1.w};
            float br[8] = {b0.x, b0.y, b0.z, b0.w, b1.x, b1.y, b1.z, b1.w};
#pragma unroll
            for (int r = 0; r < 8; ++r)
#pragma unroll
                for (int c = 0; c < 8; ++c)
                    accv[r][c] = fmaf(ar[r], br[c], accv[r][c]);
        }
        __syncthreads();
    }

    const int row_base = rowA0 + ty * 8;
    const int col_base = colB0 + tx * 8;
    int tjc[8], sjc[8];
    float invj[8];
#pragma unroll
    for (int c = 0; c < 8; ++c) {
        tjc[c] = targets[col_base + c];
        sjc[c] = sub[col_base + c];
        invj[c] = inv_norm[col_base + c];
    }
#pragma unroll
    for (int r = 0; r < 8; ++r) {
        const int gi = row_base + r;
        const int ti = targets[gi];
        const int si = sub[gi];
        const float invi = inv_norm[gi];
        float s0 = 0.f, s1 = 0.f, s2 = 0.f, s3 = 0.f;
        float s4 = 0.f, s5 = 0.f, s6 = 0.f, s7 = 0.f;
#pragma unroll
        for (int c = 0; c < 8; ++c) {
            const int gj = col_base + c;
            const float dot = accv[r][c] * invi * invj[c];
            const float dd = sqrtf(fmaxf(2.f - 2.f * dot, 1e-12f));
            const bool same = (ti == tjc[c]);
            const bool intra = (si == sjc[c]);
            const bool pos = same && (gi != gj);
            const bool neg = !same;
            const float df = (intra ? 2.4f : 2.2f) - dd;
            const float wgt = __expf(df);
            const float v = fmaxf(dd - (intra ? 1.4f : 0.7f), 0.f);
            if (pos && intra)  { s0 += v; s1 += 1.f; }
            if (pos && !intra) { s2 += v; s3 += 1.f; }
            if (neg && intra)  { s4 += df * wgt; s5 += wgt; }
            if (neg && !intra) { s6 += df * wgt; s7 += wgt; }
        }
#pragma unroll
        for (int off = 1; off < 16; off <<= 1) {
            s0 += __shfl_xor(s0, off, 64);
            s1 += __shfl_xor(s1, off, 64);
            s2 += __shfl_xor(s2, off, 64);
            s3 += __shfl_xor(s3, off, 64);
            s4 += __shfl_xor(s4, off, 64);
            s5 += __shfl_xor(s5, off, 64);
            s6 += __shfl_xor(s6, off, 64);
            s7 += __shfl_xor(s7, off, 64);
        }
        if (tx == 0) {
            float* a = acc + (size_t)gi * 8;
            atomicAdd(a + 0, s0); atomicAdd(a + 1, s1);
            atomicAdd(a + 2, s2); atomicAdd(a + 3, s3);
            atomicAdd(a + 4, s4); atomicAdd(a + 5, s5);
            atomicAdd(a + 6, s6); atomicAdd(a + 7, s7);
        }
    }
}

__global__ void finalize_kernel(const float* __restrict__ acc,
                                float* __restrict__ out, int N) {
    float s = 0.f;
    for (int i = threadIdx.x; i < N; i += THREADS) {
        const float* a = acc + (size_t)i * 8;
        s += a[0] / (a[1] + EPSV) + a[2] / (a[3] + EPSV)
           + a[4] / (a[5] + EPSV) + a[6] / (a[7] + EPSV);
    }
#pragma unroll
    for (int off = 32; off > 0; off >>= 1) s += __shfl_down(s, off, 64);
    __shared__ float red[THREADS / 64];
    if ((threadIdx.x & 63) == 0) red[threadIdx.x >> 6] = s;
    __syncthreads();
    if (threadIdx.x == 0) {
        float tot = 0.f;
#pragma unroll
        for (int w = 0; w < THREADS / 64; ++w) tot += red[w];
        out[0] = tot / (float)N;
    }
}

// ---------------------------------------------------------------------------
extern "C" void kernel_launch(void* const* d_in, const int* in_sizes, int n_in,
                              void* d_out, int out_size, void* d_ws, size_t ws_size,
                              hipStream_t stream) {
    const float* x = (const float*)d_in[0];
    const int* targets = (const int*)d_in[1];
    const int* sub = (const int*)d_in[2];
    const int N = in_sizes[1];
    const int D = in_sizes[0] / N;

    const int nbx = N / BM;
    const int T = nbx * (nbx + 1) / 2;
    const size_t sliceB = (size_t)T * 2 * 128 * 8 * sizeof(float);
    const size_t need = (size_t)N * D + 2 * sliceB;   // fp8: N*D bytes

    if (ws_size >= need) {
        unsigned char* xq = (unsigned char*)d_ws;     // N*D fp8
        float* pr = (float*)((char*)d_ws + (size_t)N * D);
        float* pc = pr + (size_t)T * 2 * 128 * 8;

        hipMemsetAsync(d_out, 0, sizeof(float), stream);
        norm_conv_fp8_kernel<<<N, THREADS, 0, stream>>>(x, xq, D);
        gram_fp8_kernel<<<T, THREADS, 0, stream>>>(xq, targets, sub,
                                                   pr, pc, D);
        finalize_sym_kernel<<<N / 16, THREADS, 0, stream>>>(
            pr, pc, (float*)d_out, N, nbx);
    } else {
        // Fallback (144 KB ws): fp32 path, known-good from round 1.
        float* inv_norm = (float*)d_ws;
        float* acc = inv_norm + N;
        hipMemsetAsync(acc, 0, (size_t)N * 8 * sizeof(float), stream);
        row_inv_norm_kernel<<<N, THREADS, 0, stream>>>(x, inv_norm, D);
        dist_loss_kernel<<<nbx * nbx, THREADS, 0, stream>>>(
            x, targets, sub, inv_norm, acc, N, D);
        finalize_kernel<<<1, THREADS, 0, stream>>>(acc, (float*)d_out, N);
    }
}

// Round 16
// 180.267 us; speedup vs baseline: 1.3145x; 1.1177x over previous
//
#include <hip/hip_runtime.h>
#include <math.h>

#define THREADS 256
#define BM 128
#define GBK 64                    // K per iteration (elements); row slice = 128B
#define EPSV 1e-5f
#define C1E 11.023176380641601f   // e^2.4
#define C2E 9.025013499434122f    // e^2.2

typedef short bf16x8 __attribute__((ext_vector_type(8)));   // 8 bf16 = 16 B
typedef float f32x4 __attribute__((ext_vector_type(4)));

// RNE float -> bf16 bit pattern
__device__ __forceinline__ unsigned short f2bf(float f) {
    unsigned int u = __float_as_uint(f);
    u += 0x7FFFu + ((u >> 16) & 1u);
    return (unsigned short)(u >> 16);
}

#define GLDS16(g, l)                                                          \
    __builtin_amdgcn_global_load_lds(                                         \
        (const __attribute__((address_space(1))) unsigned int*)(g),           \
        (__attribute__((address_space(3))) unsigned int*)(l), 16, 0, 0)

// ---------------------------------------------------------------------------
// Kernel A (sym path): NORMALIZE + convert. xb[row] = bf16(x[row]/||x[row]||).
// ---------------------------------------------------------------------------
__launch_bounds__(THREADS)
__global__ void norm_conv_kernel(const float* __restrict__ x,
                                 unsigned short* __restrict__ xb, int D) {
    const int row = blockIdx.x;
    const float4* x4 = (const float4*)(x + (size_t)row * D);
    const int tid = threadIdx.x;

    float s = 0.f;
    for (int b = tid * 2; b * 4 < D; b += THREADS * 2) {
        float4 v0 = x4[b];
        float4 v1 = x4[b + 1];
        s += v0.x * v0.x + v0.y * v0.y + v0.z * v0.z + v0.w * v0.w
           + v1.x * v1.x + v1.y * v1.y + v1.z * v1.z + v1.w * v1.w;
    }
#pragma unroll
    for (int off = 32; off > 0; off >>= 1) s += __shfl_down(s, off, 64);
    __shared__ float red[THREADS / 64 + 1];
    if ((tid & 63) == 0) red[tid >> 6] = s;
    __syncthreads();
    if (tid == 0) {
        float tot = 0.f;
#pragma unroll
        for (int w = 0; w < THREADS / 64; ++w) tot += red[w];
        red[THREADS / 64] = 1.0f / fmaxf(sqrtf(tot), 1e-12f);
    }
    __syncthreads();
    const float inv = red[THREADS / 64];

    bf16x8* out8 = (bf16x8*)(xb + (size_t)row * D);
    for (int b = tid * 2; b * 4 < D; b += THREADS * 2) {
        float4 v0 = x4[b];
        float4 v1 = x4[b + 1];
        bf16x8 o;
        o[0] = (short)f2bf(v0.x * inv); o[1] = (short)f2bf(v0.y * inv);
        o[2] = (short)f2bf(v0.z * inv); o[3] = (short)f2bf(v0.w * inv);
        o[4] = (short)f2bf(v1.x * inv); o[5] = (short)f2bf(v1.y * inv);
        o[6] = (short)f2bf(v1.z * inv); o[7] = (short)f2bf(v1.w * inv);
        out8[b >> 1] = o;
    }
}

// Plain inv-norm (fallback path).
__global__ void row_inv_norm_kernel(const float* __restrict__ x,
                                    float* __restrict__ inv_norm, int D) {
    const int row = blockIdx.x;
    const float4* x4 = (const float4*)(x + (size_t)row * D);
    const int nf4 = D >> 2;
    float s = 0.f;
    for (int i = threadIdx.x; i < nf4; i += THREADS) {
        float4 v = x4[i];
        s += v.x * v.x + v.y * v.y + v.z * v.z + v.w * v.w;
    }
#pragma unroll
    for (int off = 32; off > 0; off >>= 1) s += __shfl_down(s, off, 64);
    __shared__ float red[THREADS / 64];
    if ((threadIdx.x & 63) == 0) red[threadIdx.x >> 6] = s;
    __syncthreads();
    if (threadIdx.x == 0) {
        float tot = 0.f;
#pragma unroll
        for (int w = 0; w < THREADS / 64; ++w) tot += red[w];
        inv_norm[row] = 1.0f / fmaxf(sqrtf(tot), 1e-12f);
    }
}

// ---------------------------------------------------------------------------
// Kernel B: SYMMETRIC bf16 Gram, R11 geometry (528 tri-tiles, 256 thr, 4
// waves of 64x64) but BK=64: each row's per-iter slice is 128 B = ONE FULL
// CACHE LINE. R8's BK=32 staged 64B of every 128B line -> ~1.06 GB of line
// traffic through L2/L3 at ~8.9 TB/s; BK=64 halves line traffic to 540 MB
// at identical logical bytes. (R15's fp8 quartered slice size to 32B and
// regressed 1.5x -> line granularity, not logical bytes, is the currency.)
// 32 iters, 32 KB LDS (2 blocks/CU), 8 glds/thread/iter. XOR swizzle
// chunk' = chunk ^ (row&7) on the glds SOURCE keeps ds_read_b128 2-way
// (free). Epilogue/pr/pc identical to R11.
// vals: 0 s_pos_intra 1 cnt_pi 2 s_pos_cross 3 cnt_pc
//       4 DE_neg_intra 5 E_neg_intra 6 DE_neg_cross 7 E_neg_cross
// ---------------------------------------------------------------------------
__launch_bounds__(THREADS, 2)
__global__ void gram_sym_kernel(const unsigned short* __restrict__ xb,
                                const int* __restrict__ targets,
                                const int* __restrict__ sub,
                                float* __restrict__ pr,
                                float* __restrict__ pc,
                                int D) {
    __shared__ unsigned short As[BM * GBK];   // 16 KB
    __shared__ unsigned short Bs[BM * GBK];   // 16 KB

    // Triangular decode: tk = bx*(bx+1)/2 + by, by <= bx.
    const int tk = blockIdx.x;
    int bx = (int)((sqrtf(8.0f * tk + 1.0f) - 1.0f) * 0.5f);
    while ((bx + 1) * (bx + 2) / 2 <= tk) ++bx;
    while (bx * (bx + 1) / 2 > tk) --bx;
    const int by = tk - bx * (bx + 1) / 2;

    const int tid = threadIdx.x;
    const int w = tid >> 6;          // wave 0..3
    const int lane = tid & 63;
    const int wm = w & 1;            // row-half
    const int wn = w >> 1;           // col-half
    const int quad = lane >> 4;
    const int cl = lane & 15;

    const int rowA0 = by * BM;
    const int colB0 = bx * BM;
    const unsigned short* Abase = xb + (size_t)rowA0 * D;
    const unsigned short* Bbase = xb + (size_t)colB0 * D;

    // Staging: tile = 128 rows x 8 chunks of 16B = 1024 chunks per matrix.
    // Thread covers chunks l*256+tid, l=0..3 (4 glds per matrix). For dst
    // chunk c: row r=c>>3, slot q=c&7; source slot q' = q ^ (r&7).
    const unsigned short* sA[4];
    const unsigned short* sB[4];
    int dof[4];
#pragma unroll
    for (int l = 0; l < 4; ++l) {
        const int c = l * 256 + tid;
        const int r = c >> 3, q = (c & 7) ^ ((c >> 3) & 7);
        sA[l] = Abase + (size_t)r * D + q * 8;
        sB[l] = Bbase + (size_t)r * D + q * 8;
        dof[l] = (l * 256 + w * 64) * 8;   // wave-uniform chunk base (shorts)
    }

    f32x4 accv[4][4];
#pragma unroll
    for (int i = 0; i < 4; ++i)
#pragma unroll
        for (int j = 0; j < 4; ++j) accv[i][j] = (f32x4)(0.f);

    // Fragment offsets (shorts): row ar, k-step ks: slot (ks*4+quad)^(ar&7).
    int aoff[4][2], boff[4][2];
#pragma unroll
    for (int f = 0; f < 4; ++f) {
        const int ar = wm * 64 + f * 16 + cl;
        const int br = wn * 64 + f * 16 + cl;
#pragma unroll
        for (int ks = 0; ks < 2; ++ks) {
            aoff[f][ks] = ar * GBK + ((((ks << 2) | quad) ^ (ar & 7)) << 3);
            boff[f][ks] = br * GBK + ((((ks << 2) | quad) ^ (br & 7)) << 3);
        }
    }

    for (int kb = 0; kb < D; kb += GBK) {
#pragma unroll
        for (int l = 0; l < 4; ++l) {
            GLDS16(sA[l] + kb, As + dof[l]);
            GLDS16(sB[l] + kb, Bs + dof[l]);
        }
        __syncthreads();   // drains vmcnt: tiles in LDS

#pragma unroll
        for (int ks = 0; ks < 2; ++ks) {
            bf16x8 af[4], bfv[4];
#pragma unroll
            for (int f = 0; f < 4; ++f) {
                af[f] = *(const bf16x8*)&As[aoff[f][ks]];
                bfv[f] = *(const bf16x8*)&Bs[boff[f][ks]];
            }
#pragma unroll
            for (int mi = 0; mi < 4; ++mi)
#pragma unroll
                for (int ni = 0; ni < 4; ++ni)
                    accv[mi][ni] = __builtin_amdgcn_mfma_f32_16x16x32_bf16(
                        af[mi], bfv[ni], accv[mi][ni], 0, 0, 0);
        }
        __syncthreads();   // tiles consumed
    }

    // ---------------- epilogue pass 1: dd + row partials ----------------
    // C/D map: col = cl, row = quad*4 + reg.
    int tj[4], sj[4];
#pragma unroll
    for (int ni = 0; ni < 4; ++ni) {
        const int gc = colB0 + wn * 64 + ni * 16 + cl;
        tj[ni] = targets[gc];
        sj[ni] = sub[gc];
    }

#pragma unroll
    for (int mi = 0; mi < 4; ++mi) {
#pragma unroll
        for (int r = 0; r < 4; ++r) {
            const int gi = rowA0 + wm * 64 + mi * 16 + quad * 4 + r;
            const int ti = targets[gi];
            const int si = sub[gi];

            float s0 = 0.f, s1 = 0.f, s2 = 0.f, s3 = 0.f;
            float s4 = 0.f, s5 = 0.f, s6 = 0.f, s7 = 0.f;
#pragma unroll
            for (int ni = 0; ni < 4; ++ni) {
                const int gj = colB0 + wn * 64 + ni * 16 + cl;
                const float d2 = fmaf(-2.f, accv[mi][ni][r], 2.f);
                const float dd = sqrtf(fmaxf(d2, 1e-12f));
                accv[mi][ni][r] = dd;          // overwrite: pass 2 reuses
                const bool same = (ti == tj[ni]);
                const bool intra = (si == sj[ni]);
                const bool pos = same && (gi != gj);
                const bool neg = !same;
                const float mg = intra ? 1.4f : 0.7f;
                const float v = fmaxf(dd - mg, 0.f);
                const float e = __expf(-dd);   // e^alpha folded in finalize
                const float de = dd * e;
                if (pos && intra)  { s0 += v;  s1 += 1.f; }
                if (pos && !intra) { s2 += v;  s3 += 1.f; }
                if (neg && intra)  { s4 += de; s5 += e; }
                if (neg && !intra) { s6 += de; s7 += e; }
            }
#pragma unroll
            for (int off = 1; off < 16; off <<= 1) {
                s0 += __shfl_xor(s0, off, 64);
                s1 += __shfl_xor(s1, off, 64);
                s2 += __shfl_xor(s2, off, 64);
                s3 += __shfl_xor(s3, off, 64);
                s4 += __shfl_xor(s4, off, 64);
                s5 += __shfl_xor(s5, off, 64);
                s6 += __shfl_xor(s6, off, 64);
                s7 += __shfl_xor(s7, off, 64);
            }
            if (cl == 0) {
                const int rloc = wm * 64 + mi * 16 + quad * 4 + r;
                float* dst = pr +
                    ((size_t)(blockIdx.x * 2 + wn) * 128 + rloc) * 8;
                float4 p0 = {s0, s1, s2, s3};
                float4 p1 = {s4, s5, s6, s7};
                *(float4*)(dst) = p0;
                *(float4*)(dst + 4) = p1;
            }
        }
    }

    // ---------------- epilogue pass 2: col partials ----------------
    const float om = (bx == by) ? 0.f : 1.f;   // diag tiles: zero col side
#pragma unroll
    for (int ni = 0; ni < 4; ++ni) {
        const int gj = colB0 + wn * 64 + ni * 16 + cl;
        const int tjc = tj[ni];
        const int sjc = sj[ni];
        float s0 = 0.f, s1 = 0.f, s2 = 0.f, s3 = 0.f;
        float s4 = 0.f, s5 = 0.f, s6 = 0.f, s7 = 0.f;
#pragma unroll
        for (int mi = 0; mi < 4; ++mi) {
#pragma unroll
            for (int r = 0; r < 4; ++r) {
                const int gi = rowA0 + wm * 64 + mi * 16 + quad * 4 + r;
                const int ti = targets[gi];     // L1-hot reload
                const int si = sub[gi];
                const float dd = accv[mi][ni][r];
                const bool same = (ti == tjc);
                const bool intra = (si == sjc);
                const bool pos = same && (gi != gj);
                const bool neg = !same;
                const float mg = intra ? 1.4f : 0.7f;
                const float v = fmaxf(dd - mg, 0.f);
                const float e = __expf(-dd);
                const float de = dd * e;
                if (pos && intra)  { s0 += v;  s1 += 1.f; }
                if (pos && !intra) { s2 += v;  s3 += 1.f; }
                if (neg && intra)  { s4 += de; s5 += e; }
                if (neg && !intra) { s6 += de; s7 += e; }
            }
        }
        s0 += __shfl_xor(s0, 16, 64); s0 += __shfl_xor(s0, 32, 64);
        s1 += __shfl_xor(s1, 16, 64); s1 += __shfl_xor(s1, 32, 64);
        s2 += __shfl_xor(s2, 16, 64); s2 += __shfl_xor(s2, 32, 64);
        s3 += __shfl_xor(s3, 16, 64); s3 += __shfl_xor(s3, 32, 64);
        s4 += __shfl_xor(s4, 16, 64); s4 += __shfl_xor(s4, 32, 64);
        s5 += __shfl_xor(s5, 16, 64); s5 += __shfl_xor(s5, 32, 64);
        s6 += __shfl_xor(s6, 16, 64); s6 += __shfl_xor(s6, 32, 64);
        s7 += __shfl_xor(s7, 16, 64); s7 += __shfl_xor(s7, 32, 64);
        if (lane < 16) {
            const int colloc = wn * 64 + ni * 16 + lane;
            float* dst = pc +
                ((size_t)(blockIdx.x * 2 + wm) * 128 + colloc) * 8;
            float4 p0 = {s0 * om, s1 * om, s2 * om, s3 * om};
            float4 p1 = {s4 * om, s5 * om, s6 * om, s7 * om};
            *(float4*)(dst) = p0;
            *(float4*)(dst + 4) = p1;
        }
    }
}

// ---------------------------------------------------------------------------
// Kernel C: gather 64 slices per row, combine ratios, global mean.
// (Identical to R11 — pr/pc layout unchanged.)
// ---------------------------------------------------------------------------
__global__ void finalize_sym_kernel(const float* __restrict__ pr,
                                    const float* __restrict__ pc,
                                    float* __restrict__ out, int N, int nbx) {
    const int tid = threadIdx.x;
    const int rloc16 = tid >> 4;
    const int st = tid & 15;
    const int i = blockIdx.x * 16 + rloc16;
    const int B = i >> 7;
    const int rl = i & 127;
    const int nrow = (nbx - B) * 2;

    float a0 = 0.f, a1 = 0.f, a2 = 0.f, a3 = 0.f;
    float a4 = 0.f, a5 = 0.f, a6 = 0.f, a7 = 0.f;
#pragma unroll
    for (int s4i = 0; s4i < 4; ++s4i) {
        const int sidx = st * 4 + s4i;
        const float* base;
        if (sidx < nrow) {
            const int bxx = B + (sidx >> 1);
            const int t = bxx * (bxx + 1) / 2 + B;
            base = pr + ((size_t)(t * 2 + (sidx & 1)) * 128 + rl) * 8;
        } else {
            const int m = sidx - nrow;
            const int t = B * (B + 1) / 2 + (m >> 1);
            base = pc + ((size_t)(t * 2 + (m & 1)) * 128 + rl) * 8;
        }
        float4 u0 = *(const float4*)(base);
        float4 u1 = *(const float4*)(base + 4);
        a0 += u0.x; a1 += u0.y; a2 += u0.z; a3 += u0.w;
        a4 += u1.x; a5 += u1.y; a6 += u1.z; a7 += u1.w;
    }
#pragma unroll
    for (int off = 1; off < 16; off <<= 1) {
        a0 += __shfl_xor(a0, off, 64);
        a1 += __shfl_xor(a1, off, 64);
        a2 += __shfl_xor(a2, off, 64);
        a3 += __shfl_xor(a3, off, 64);
        a4 += __shfl_xor(a4, off, 64);
        a5 += __shfl_xor(a5, off, 64);
        a6 += __shfl_xor(a6, off, 64);
        a7 += __shfl_xor(a7, off, 64);
    }
    __shared__ float lred[16];
    if (st == 0) {
        const float l = a0 / (a1 + EPSV) + a2 / (a3 + EPSV)
            + (C1E * fmaf(2.4f, a5, -a4)) / (C1E * a5 + EPSV)
            + (C2E * fmaf(2.2f, a7, -a6)) / (C2E * a7 + EPSV);
        lred[rloc16] = l;
    }
    __syncthreads();
    if (tid == 0) {
        float tot = 0.f;
#pragma unroll
        for (int k2 = 0; k2 < 16; ++k2) tot += lred[k2];
        atomicAdd(out, tot / (float)N);
    }
}

// ---------------------------------------------------------------------------
// Fallback path (144 KB ws): fp32 tile GEMM + atomic epilogue (R1, known-good)
// ---------------------------------------------------------------------------
__launch_bounds__(THREADS, 2)
__global__ void dist_loss_kernel(const float* __restrict__ x,
                                 const int* __restrict__ targets,
                                 const int* __restrict__ sub,
                                 const float* __restrict__ inv_norm,
                                 float* __restrict__ acc,
                                 int N, int D) {
    __shared__ float Asf[16][128];
    __shared__ float Bsf[16][128];

    const int nbx = N / 128;
    const int bx = blockIdx.x % nbx;
    const int by = blockIdx.x / nbx;
    const int tid = threadIdx.x;
    const int tx = tid & 15;
    const int ty = tid >> 4;
    const int rowA0 = by * 128;
    const int colB0 = bx * 128;
    const float* Abase = x + (size_t)rowA0 * D;
    const float* Bbase = x + (size_t)colB0 * D;

    float accv[8][8];
#pragma unroll
    for (int r = 0; r < 8; ++r)
#pragma unroll
        for (int c = 0; c < 8; ++c) accv[r][c] = 0.f;

    for (int kb = 0; kb < D; kb += 16) {
#pragma unroll
        for (int l = 0; l < 2; ++l) {
            const int f = tid + l * THREADS;
            const int row = f >> 2;
            const int kq = (f & 3) << 2;
            float4 va = *(const float4*)(Abase + (size_t)row * D + kb + kq);
            float4 vb = *(const float4*)(Bbase + (size_t)row * D + kb + kq);
            Asf[kq + 0][row] = va.x; Asf[kq + 1][row] = va.y;
            Asf[kq + 2][row] = va.z; Asf[kq + 3][row] = va.w;
            Bsf[kq + 0][row] = vb.x; Bsf[kq + 1][row] = vb.y;
            Bsf[kq + 2][row] = vb.z; Bsf[kq + 3][row] = vb.w;
        }
        __syncthreads();
#pragma unroll
        for (int k = 0; k < 16; ++k) {
            float4 a0 = *(const float4*)&Asf[k][ty * 8];
            float4 a1 = *(const float4*)&Asf[k][ty * 8 + 4];
            float4 b0 = *(const float4*)&Bsf[k][tx * 8];
            float4 b1 = *(const float4*)&Bsf[k][tx * 8 + 4];
            float ar[8] = {a0.x, a0.y, a0.z, a0.w, a1.x, a1.y, a1.z, a1.w};
            float br[8] = {b0.x, b0.y, b0.z, b0.w, b1.x, b1.y, b1.z, b1.w};
#pragma unroll
            for (int r = 0; r < 8; ++r)
#pragma unroll
                for (int c = 0; c < 8; ++c)
                    accv[r][c] = fmaf(ar[r], br[c], accv[r][c]);
        }
        __syncthreads();
    }

    const int row_base = rowA0 + ty * 8;
    const int col_base = colB0 + tx * 8;
    int tjc[8], sjc[8];
    float invj[8];
#pragma unroll
    for (int c = 0; c < 8; ++c) {
        tjc[c] = targets[col_base + c];
        sjc[c] = sub[col_base + c];
        invj[c] = inv_norm[col_base + c];
    }
#pragma unroll
    for (int r = 0; r < 8; ++r) {
        const int gi = row_base + r;
        const int ti = targets[gi];
        const int si = sub[gi];
        const float invi = inv_norm[gi];
        float s0 = 0.f, s1 = 0.f, s2 = 0.f, s3 = 0.f;
        float s4 = 0.f, s5 = 0.f, s6 = 0.f, s7 = 0.f;
#pragma unroll
        for (int c = 0; c < 8; ++c) {
            const int gj = col_base + c;
            const float dot = accv[r][c] * invi * invj[c];
            const float dd = sqrtf(fmaxf(2.f - 2.f * dot, 1e-12f));
            const bool same = (ti == tjc[c]);
            const bool intra = (si == sjc[c]);
            const bool pos = same && (gi != gj);
            const bool neg = !same;
            const float df = (intra ? 2.4f : 2.2f) - dd;
            const float wgt = __expf(df);
            const float v = fmaxf(dd - (intra ? 1.4f : 0.7f), 0.f);
            if (pos && intra)  { s0 += v; s1 += 1.f; }
            if (pos && !intra) { s2 += v; s3 += 1.f; }
            if (neg && intra)  { s4 += df * wgt; s5 += wgt; }
            if (neg && !intra) { s6 += df * wgt; s7 += wgt; }
        }
#pragma unroll
        for (int off = 1; off < 16; off <<= 1) {
            s0 += __shfl_xor(s0, off, 64);
            s1 += __shfl_xor(s1, off, 64);
            s2 += __shfl_xor(s2, off, 64);
            s3 += __shfl_xor(s3, off, 64);
            s4 += __shfl_xor(s4, off, 64);
            s5 += __shfl_xor(s5, off, 64);
            s6 += __shfl_xor(s6, off, 64);
            s7 += __shfl_xor(s7, off, 64);
        }
        if (tx == 0) {
            float* a = acc + (size_t)gi * 8;
            atomicAdd(a + 0, s0); atomicAdd(a + 1, s1);
            atomicAdd(a + 2, s2); atomicAdd(a + 3, s3);
            atomicAdd(a + 4, s4); atomicAdd(a + 5, s5);
            atomicAdd(a + 6, s6); atomicAdd(a + 7, s7);
        }
    }
}

__global__ void finalize_kernel(const float* __restrict__ acc,
                                float* __restrict__ out, int N) {
    float s = 0.f;
    for (int i = threadIdx.x; i < N; i += THREADS) {
        const float* a = acc + (size_t)i * 8;
        s += a[0] / (a[1] + EPSV) + a[2] / (a[3] + EPSV)
           + a[4] / (a[5] + EPSV) + a[6] / (a[7] + EPSV);
    }
#pragma unroll
    for (int off = 32; off > 0; off >>= 1) s += __shfl_down(s, off, 64);
    __shared__ float red[THREADS / 64];
    if ((threadIdx.x & 63) == 0) red[threadIdx.x >> 6] = s;
    __syncthreads();
    if (threadIdx.x == 0) {
        float tot = 0.f;
#pragma unroll
        for (int w = 0; w < THREADS / 64; ++w) tot += red[w];
        out[0] = tot / (float)N;
    }
}

// ---------------------------------------------------------------------------
extern "C" void kernel_launch(void* const* d_in, const int* in_sizes, int n_in,
                              void* d_out, int out_size, void* d_ws, size_t ws_size,
                              hipStream_t stream) {
    const float* x = (const float*)d_in[0];
    const int* targets = (const int*)d_in[1];
    const int* sub = (const int*)d_in[2];
    const int N = in_sizes[1];
    const int D = in_sizes[0] / N;

    const int nbx = N / BM;
    const int T = nbx * (nbx + 1) / 2;
    const size_t sliceB = (size_t)T * 2 * 128 * 8 * sizeof(float);
    const size_t need = (size_t)N * D * 2 + 2 * sliceB;

    if (ws_size >= need) {
        unsigned short* xb = (unsigned short*)d_ws;           // N*D bf16
        float* pr = (float*)((char*)d_ws + (size_t)N * D * 2);
        float* pc = pr + (size_t)T * 2 * 128 * 8;

        hipMemsetAsync(d_out, 0, sizeof(float), stream);
        norm_conv_kernel<<<N, THREADS, 0, stream>>>(x, xb, D);
        gram_sym_kernel<<<T, THREADS, 0, stream>>>(xb, targets, sub,
                                                   pr, pc, D);
        finalize_sym_kernel<<<N / 16, THREADS, 0, stream>>>(
            pr, pc, (float*)d_out, N, nbx);
    } else {
        // Fallback (144 KB ws): fp32 path, known-good from round 1.
        float* inv_norm = (float*)d_ws;
        float* acc = inv_norm + N;
        hipMemsetAsync(acc, 0, (size_t)N * 8 * sizeof(float), stream);
        row_inv_norm_kernel<<<N, THREADS, 0, stream>>>(x, inv_norm, D);
        dist_loss_kernel<<<nbx * nbx, THREADS, 0, stream>>>(
            x, targets, sub, inv_norm, acc, N, D);
        finalize_kernel<<<1, THREADS, 0, stream>>>(acc, (float*)d_out, N);
    }
}

// Round 17
// 165.714 us; speedup vs baseline: 1.4299x; 1.0878x over previous
//
#include <hip/hip_runtime.h>
#include <math.h>

#define THREADS 256
#define BM 128
#define QBK 128                   // fp8 K per iteration; row slice = 128 B line
#define EPSV 1e-5f
#define C1E 11.023176380641601f   // e^2.4
#define C2E 9.025013499434122f    // e^2.2
#define FP8_SCALE 256.0f          // power-of-2 row scale into e4m3 range
#define INV_SCALE2 1.52587890625e-5f   // 1/65536, exact

typedef float f32x4 __attribute__((ext_vector_type(4)));

// ---------------------------------------------------------------------------
// Kernel A (fp8 path): normalize row, scale by 256, convert to OCP e4m3.
// (R15-proven: absmax 0.0 on the final scalar.)
// ---------------------------------------------------------------------------
__launch_bounds__(THREADS)
__global__ void norm_conv_fp8_kernel(const float* __restrict__ x,
                                     unsigned char* __restrict__ xq, int D) {
    const int row = blockIdx.x;
    const float4* x4 = (const float4*)(x + (size_t)row * D);
    const int tid = threadIdx.x;

    float s = 0.f;
    for (int b = tid * 2; b * 4 < D; b += THREADS * 2) {
        float4 v0 = x4[b];
        float4 v1 = x4[b + 1];
        s += v0.x * v0.x + v0.y * v0.y + v0.z * v0.z + v0.w * v0.w
           + v1.x * v1.x + v1.y * v1.y + v1.z * v1.z + v1.w * v1.w;
    }
#pragma unroll
    for (int off = 32; off > 0; off >>= 1) s += __shfl_down(s, off, 64);
    __shared__ float red[THREADS / 64 + 1];
    if ((tid & 63) == 0) red[tid >> 6] = s;
    __syncthreads();
    if (tid == 0) {
        float tot = 0.f;
#pragma unroll
        for (int w = 0; w < THREADS / 64; ++w) tot += red[w];
        red[THREADS / 64] = FP8_SCALE / fmaxf(sqrtf(tot), 1e-12f);
    }
    __syncthreads();
    const float sc = red[THREADS / 64];

    int2* out = (int2*)(xq + (size_t)row * D);
    for (int b = tid * 2; b * 4 < D; b += THREADS * 2) {
        float4 v0 = x4[b];
        float4 v1 = x4[b + 1];
        int lo = __builtin_amdgcn_cvt_pk_fp8_f32(v0.x * sc, v0.y * sc, 0, 0);
        lo = __builtin_amdgcn_cvt_pk_fp8_f32(v0.z * sc, v0.w * sc, lo, 1);
        int hi = __builtin_amdgcn_cvt_pk_fp8_f32(v1.x * sc, v1.y * sc, 0, 0);
        hi = __builtin_amdgcn_cvt_pk_fp8_f32(v1.z * sc, v1.w * sc, hi, 1);
        int2 o; o.x = lo; o.y = hi;
        out[b >> 1] = o;
    }
}

// Plain inv-norm (fallback path).
__global__ void row_inv_norm_kernel(const float* __restrict__ x,
                                    float* __restrict__ inv_norm, int D) {
    const int row = blockIdx.x;
    const float4* x4 = (const float4*)(x + (size_t)row * D);
    const int nf4 = D >> 2;
    float s = 0.f;
    for (int i = threadIdx.x; i < nf4; i += THREADS) {
        float4 v = x4[i];
        s += v.x * v.x + v.y * v.y + v.z * v.z + v.w * v.w;
    }
#pragma unroll
    for (int off = 32; off > 0; off >>= 1) s += __shfl_down(s, off, 64);
    __shared__ float red[THREADS / 64];
    if ((threadIdx.x & 63) == 0) red[threadIdx.x >> 6] = s;
    __syncthreads();
    if (threadIdx.x == 0) {
        float tot = 0.f;
#pragma unroll
        for (int w = 0; w < THREADS / 64; ++w) tot += red[w];
        inv_norm[row] = 1.0f / fmaxf(sqrtf(tot), 1e-12f);
    }
}

#define GLDS16(g, l)                                                          \
    __builtin_amdgcn_global_load_lds(                                         \
        (const __attribute__((address_space(1))) unsigned int*)(g),           \
        (__attribute__((address_space(3))) unsigned int*)(l), 16, 0, 0)

// ---------------------------------------------------------------------------
// Kernel B: SYMMETRIC fp8 Gram, BK=128 (row slice = ONE FULL 128B LINE —
// fixes R15's 32B-slice line-waste) on the proven 528-tile / 256-thread /
// 64x64-wave geometry. 16 iters (vs R16's 32): per drain, each wave runs
// 4 K-steps = 64 MFMAs + 32 ds_read_b64. Line traffic 540 (R16 bf16) ->
// 264 MB. LDS 2x16KB = 32 KB (2 blocks/CU). Chunk XOR swizzle q'=q^(r&7)
// on the glds SOURCE spreads fragment b64 reads across banks.
// fp8 numerics R15-proven (absmax 0.0); x256 pow2 scale unfolds exactly.
// vals: 0 s_pos_intra 1 cnt_pi 2 s_pos_cross 3 cnt_pc
//       4 DE_neg_intra 5 E_neg_intra 6 DE_neg_cross 7 E_neg_cross
// ---------------------------------------------------------------------------
__launch_bounds__(THREADS, 2)
__global__ void gram_fp8_kernel(const unsigned char* __restrict__ xq,
                                const int* __restrict__ targets,
                                const int* __restrict__ sub,
                                float* __restrict__ pr,
                                float* __restrict__ pc,
                                int D) {
    __shared__ unsigned char As[BM * QBK];   // 16 KB
    __shared__ unsigned char Bs[BM * QBK];   // 16 KB

    // Triangular decode: tk = bx*(bx+1)/2 + by, by <= bx.
    const int tk = blockIdx.x;
    int bx = (int)((sqrtf(8.0f * tk + 1.0f) - 1.0f) * 0.5f);
    while ((bx + 1) * (bx + 2) / 2 <= tk) ++bx;
    while (bx * (bx + 1) / 2 > tk) --bx;
    const int by = tk - bx * (bx + 1) / 2;

    const int tid = threadIdx.x;
    const int w = tid >> 6;          // wave 0..3
    const int lane = tid & 63;
    const int wm = w & 1;            // row-half
    const int wn = w >> 1;           // col-half
    const int quad = lane >> 4;
    const int cl = lane & 15;

    const int rowA0 = by * BM;
    const int colB0 = bx * BM;
    const unsigned char* Abase = xq + (size_t)rowA0 * D;
    const unsigned char* Bbase = xq + (size_t)colB0 * D;

    // Staging: tile = 128 rows x 8 chunks of 16B = 1024 chunks per matrix.
    // Thread covers chunks l*256+tid (l=0..3) per matrix -> 8 glds/iter.
    // Dst chunk c: row r=c>>3, slot q=c&7; source slot q' = q ^ (r&7).
    const unsigned char* sA[4];
    const unsigned char* sB[4];
    int dof[4];
#pragma unroll
    for (int l = 0; l < 4; ++l) {
        const int c = l * 256 + tid;
        const int r = c >> 3, q = (c & 7) ^ ((c >> 3) & 7);
        sA[l] = Abase + (size_t)r * D + q * 16;
        sB[l] = Bbase + (size_t)r * D + q * 16;
        dof[l] = (l * 256 + w * 64) * 16;   // wave-uniform byte base
    }

    f32x4 accv[4][4];
#pragma unroll
    for (int i = 0; i < 4; ++i)
#pragma unroll
        for (int j = 0; j < 4; ++j) accv[i][j] = (f32x4)(0.f);

    // Fragment byte offsets: row r, K-step ks: 8B slot sl = ks*4+quad;
    // chunk = sl>>1 stored at (sl>>1)^(r&7); byte = r*128 + chunk'*16 +
    // (sl&1)*8.
    int aoff[4][4], boff[4][4];
#pragma unroll
    for (int f = 0; f < 4; ++f) {
        const int ar = wm * 64 + f * 16 + cl;
        const int br = wn * 64 + f * 16 + cl;
#pragma unroll
        for (int ks = 0; ks < 4; ++ks) {
            const int sl = ks * 4 + quad;
            aoff[f][ks] = ar * QBK + (((sl >> 1) ^ (ar & 7)) << 4)
                        + ((sl & 1) << 3);
            boff[f][ks] = br * QBK + (((sl >> 1) ^ (br & 7)) << 4)
                        + ((sl & 1) << 3);
        }
    }

    for (int kb = 0; kb < D; kb += QBK) {
#pragma unroll
        for (int l = 0; l < 4; ++l) {
            GLDS16(sA[l] + kb, As + dof[l]);
            GLDS16(sB[l] + kb, Bs + dof[l]);
        }
        __syncthreads();   // drains vmcnt: tiles in LDS

#pragma unroll
        for (int ks = 0; ks < 4; ++ks) {
            long af[4], bfv[4];
#pragma unroll
            for (int f = 0; f < 4; ++f) {
                af[f] = *(const long*)&As[aoff[f][ks]];
                bfv[f] = *(const long*)&Bs[boff[f][ks]];
            }
#pragma unroll
            for (int mi = 0; mi < 4; ++mi)
#pragma unroll
                for (int ni = 0; ni < 4; ++ni)
                    accv[mi][ni] =
                        __builtin_amdgcn_mfma_f32_16x16x32_fp8_fp8(
                            af[mi], bfv[ni], accv[mi][ni], 0, 0, 0);
        }
        __syncthreads();   // tiles consumed
    }

    // ---------------- epilogue pass 1: dd + row partials ----------------
    // C/D map: col = cl, row = quad*4 + reg. Dots carry scale 65536.
    int tj[4], sj[4];
#pragma unroll
    for (int ni = 0; ni < 4; ++ni) {
        const int gc = colB0 + wn * 64 + ni * 16 + cl;
        tj[ni] = targets[gc];
        sj[ni] = sub[gc];
    }

#pragma unroll
    for (int mi = 0; mi < 4; ++mi) {
#pragma unroll
        for (int r = 0; r < 4; ++r) {
            const int gi = rowA0 + wm * 64 + mi * 16 + quad * 4 + r;
            const int ti = targets[gi];
            const int si = sub[gi];

            float s0 = 0.f, s1 = 0.f, s2 = 0.f, s3 = 0.f;
            float s4 = 0.f, s5 = 0.f, s6 = 0.f, s7 = 0.f;
#pragma unroll
            for (int ni = 0; ni < 4; ++ni) {
                const int gj = colB0 + wn * 64 + ni * 16 + cl;
                const float d2 =
                    fmaf(-2.0f * INV_SCALE2, accv[mi][ni][r], 2.0f);
                const float dd = sqrtf(fmaxf(d2, 1e-12f));
                accv[mi][ni][r] = dd;          // overwrite: pass 2 reuses
                const bool same = (ti == tj[ni]);
                const bool intra = (si == sj[ni]);
                const bool pos = same && (gi != gj);
                const bool neg = !same;
                const float mg = intra ? 1.4f : 0.7f;
                const float v = fmaxf(dd - mg, 0.f);
                const float e = __expf(-dd);   // e^alpha folded in finalize
                const float de = dd * e;
                if (pos && intra)  { s0 += v;  s1 += 1.f; }
                if (pos && !intra) { s2 += v;  s3 += 1.f; }
                if (neg && intra)  { s4 += de; s5 += e; }
                if (neg && !intra) { s6 += de; s7 += e; }
            }
#pragma unroll
            for (int off = 1; off < 16; off <<= 1) {
                s0 += __shfl_xor(s0, off, 64);
                s1 += __shfl_xor(s1, off, 64);
                s2 += __shfl_xor(s2, off, 64);
                s3 += __shfl_xor(s3, off, 64);
                s4 += __shfl_xor(s4, off, 64);
                s5 += __shfl_xor(s5, off, 64);
                s6 += __shfl_xor(s6, off, 64);
                s7 += __shfl_xor(s7, off, 64);
            }
            if (cl == 0) {
                const int rloc = wm * 64 + mi * 16 + quad * 4 + r;
                float* dst = pr +
                    ((size_t)(blockIdx.x * 2 + wn) * 128 + rloc) * 8;
                float4 p0 = {s0, s1, s2, s3};
                float4 p1 = {s4, s5, s6, s7};
                *(float4*)(dst) = p0;
                *(float4*)(dst + 4) = p1;
            }
        }
    }

    // ---------------- epilogue pass 2: col partials ----------------
    const float om = (bx == by) ? 0.f : 1.f;   // diag tiles: zero col side
#pragma unroll
    for (int ni = 0; ni < 4; ++ni) {
        const int gj = colB0 + wn * 64 + ni * 16 + cl;
        const int tjc = tj[ni];
        const int sjc = sj[ni];
        float s0 = 0.f, s1 = 0.f, s2 = 0.f, s3 = 0.f;
        float s4 = 0.f, s5 = 0.f, s6 = 0.f, s7 = 0.f;
#pragma unroll
        for (int mi = 0; mi < 4; ++mi) {
#pragma unroll
            for (int r = 0; r < 4; ++r) {
                const int gi = rowA0 + wm * 64 + mi * 16 + quad * 4 + r;
                const int ti = targets[gi];     // L1-hot reload
                const int si = sub[gi];
                const float dd = accv[mi][ni][r];
                const bool same = (ti == tjc);
                const bool intra = (si == sjc);
                const bool pos = same && (gi != gj);
                const bool neg = !same;
                const float mg = intra ? 1.4f : 0.7f;
                const float v = fmaxf(dd - mg, 0.f);
                const float e = __expf(-dd);
                const float de = dd * e;
                if (pos && intra)  { s0 += v;  s1 += 1.f; }
                if (pos && !intra) { s2 += v;  s3 += 1.f; }
                if (neg && intra)  { s4 += de; s5 += e; }
                if (neg && !intra) { s6 += de; s7 += e; }
            }
        }
        s0 += __shfl_xor(s0, 16, 64); s0 += __shfl_xor(s0, 32, 64);
        s1 += __shfl_xor(s1, 16, 64); s1 += __shfl_xor(s1, 32, 64);
        s2 += __shfl_xor(s2, 16, 64); s2 += __shfl_xor(s2, 32, 64);
        s3 += __shfl_xor(s3, 16, 64); s3 += __shfl_xor(s3, 32, 64);
        s4 += __shfl_xor(s4, 16, 64); s4 += __shfl_xor(s4, 32, 64);
        s5 += __shfl_xor(s5, 16, 64); s5 += __shfl_xor(s5, 32, 64);
        s6 += __shfl_xor(s6, 16, 64); s6 += __shfl_xor(s6, 32, 64);
        s7 += __shfl_xor(s7, 16, 64); s7 += __shfl_xor(s7, 32, 64);
        if (lane < 16) {
            const int colloc = wn * 64 + ni * 16 + lane;
            float* dst = pc +
                ((size_t)(blockIdx.x * 2 + wm) * 128 + colloc) * 8;
            float4 p0 = {s0 * om, s1 * om, s2 * om, s3 * om};
            float4 p1 = {s4 * om, s5 * om, s6 * om, s7 * om};
            *(float4*)(dst) = p0;
            *(float4*)(dst + 4) = p1;
        }
    }
}

// ---------------------------------------------------------------------------
// Kernel C: gather 64 slices per row, combine ratios, global mean.
// ---------------------------------------------------------------------------
__global__ void finalize_sym_kernel(const float* __restrict__ pr,
                                    const float* __restrict__ pc,
                                    float* __restrict__ out, int N, int nbx) {
    const int tid = threadIdx.x;
    const int rloc16 = tid >> 4;
    const int st = tid & 15;
    const int i = blockIdx.x * 16 + rloc16;
    const int B = i >> 7;
    const int rl = i & 127;
    const int nrow = (nbx - B) * 2;

    float a0 = 0.f, a1 = 0.f, a2 = 0.f, a3 = 0.f;
    float a4 = 0.f, a5 = 0.f, a6 = 0.f, a7 = 0.f;
#pragma unroll
    for (int s4i = 0; s4i < 4; ++s4i) {
        const int sidx = st * 4 + s4i;
        const float* base;
        if (sidx < nrow) {
            const int bxx = B + (sidx >> 1);
            const int t = bxx * (bxx + 1) / 2 + B;
            base = pr + ((size_t)(t * 2 + (sidx & 1)) * 128 + rl) * 8;
        } else {
            const int m = sidx - nrow;
            const int t = B * (B + 1) / 2 + (m >> 1);
            base = pc + ((size_t)(t * 2 + (m & 1)) * 128 + rl) * 8;
        }
        float4 u0 = *(const float4*)(base);
        float4 u1 = *(const float4*)(base + 4);
        a0 += u0.x; a1 += u0.y; a2 += u0.z; a3 += u0.w;
        a4 += u1.x; a5 += u1.y; a6 += u1.z; a7 += u1.w;
    }
#pragma unroll
    for (int off = 1; off < 16; off <<= 1) {
        a0 += __shfl_xor(a0, off, 64);
        a1 += __shfl_xor(a1, off, 64);
        a2 += __shfl_xor(a2, off, 64);
        a3 += __shfl_xor(a3, off, 64);
        a4 += __shfl_xor(a4, off, 64);
        a5 += __shfl_xor(a5, off, 64);
        a6 += __shfl_xor(a6, off, 64);
        a7 += __shfl_xor(a7, off, 64);
    }
    __shared__ float lred[16];
    if (st == 0) {
        const float l = a0 / (a1 + EPSV) + a2 / (a3 + EPSV)
            + (C1E * fmaf(2.4f, a5, -a4)) / (C1E * a5 + EPSV)
            + (C2E * fmaf(2.2f, a7, -a6)) / (C2E * a7 + EPSV);
        lred[rloc16] = l;
    }
    __syncthreads();
    if (tid == 0) {
        float tot = 0.f;
#pragma unroll
        for (int k2 = 0; k2 < 16; ++k2) tot += lred[k2];
        atomicAdd(out, tot / (float)N);
    }
}

// ---------------------------------------------------------------------------
// Fallback path (144 KB ws): fp32 tile GEMM + atomic epilogue (R1, known-good)
// ---------------------------------------------------------------------------
__launch_bounds__(THREADS, 2)
__global__ void dist_loss_kernel(const float* __restrict__ x,
                                 const int* __restrict__ targets,
                                 const int* __restrict__ sub,
                                 const float* __restrict__ inv_norm,
                                 float* __restrict__ acc,
                                 int N, int D) {
    __shared__ float Asf[16][128];
    __shared__ float Bsf[16][128];

    const int nbx = N / 128;
    const int bx = blockIdx.x % nbx;
    const int by = blockIdx.x / nbx;
    const int tid = threadIdx.x;
    const int tx = tid & 15;
    const int ty = tid >> 4;
    const int rowA0 = by * 128;
    const int colB0 = bx * 128;
    const float* Abase = x + (size_t)rowA0 * D;
    const float* Bbase = x + (size_t)colB0 * D;

    float accv[8][8];
#pragma unroll
    for (int r = 0; r < 8; ++r)
#pragma unroll
        for (int c = 0; c < 8; ++c) accv[r][c] = 0.f;

    for (int kb = 0; kb < D; kb += 16) {
#pragma unroll
        for (int l = 0; l < 2; ++l) {
            const int f = tid + l * THREADS;
            const int row = f >> 2;
            const int kq = (f & 3) << 2;
            float4 va = *(const float4*)(Abase + (size_t)row * D + kb + kq);
            float4 vb = *(const float4*)(Bbase + (size_t)row * D + kb + kq);
            Asf[kq + 0][row] = va.x; Asf[kq + 1][row] = va.y;
            Asf[kq + 2][row] = va.z; Asf[kq + 3][row] = va.w;
            Bsf[kq + 0][row] = vb.x; Bsf[kq + 1][row] = vb.y;
            Bsf[kq + 2][row] = vb.z; Bsf[kq + 3][row] = vb.w;
        }
        __syncthreads();
#pragma unroll
        for (int k = 0; k < 16; ++k) {
            float4 a0 = *(const float4*)&Asf[k][ty * 8];
            float4 a1 = *(const float4*)&Asf[k][ty * 8 + 4];
            float4 b0 = *(const float4*)&Bsf[k][tx * 8];
            float4 b1 = *(const float4*)&Bsf[k][tx * 8 + 4];
            float ar[8] = {a0.x, a0.y, a0.z, a0.w, a1.x, a1.y, a1.z, a1.w};
            float br[8] = {b0.x, b0.y, b0.z, b0.w, b1.x, b1.y, b1.z, b1.w};
#pragma unroll
            for (int r = 0; r < 8; ++r)
#pragma unroll
                for (int c = 0; c < 8; ++c)
                    accv[r][c] = fmaf(ar[r], br[c], accv[r][c]);
        }
        __syncthreads();
    }

    const int row_base = rowA0 + ty * 8;
    const int col_base = colB0 + tx * 8;
    int tjc[8], sjc[8];
    float invj[8];
#pragma unroll
    for (int c = 0; c < 8; ++c) {
        tjc[c] = targets[col_base + c];
        sjc[c] = sub[col_base + c];
        invj[c] = inv_norm[col_base + c];
    }
#pragma unroll
    for (int r = 0; r < 8; ++r) {
        const int gi = row_base + r;
        const int ti = targets[gi];
        const int si = sub[gi];
        const float invi = inv_norm[gi];
        float s0 = 0.f, s1 = 0.f, s2 = 0.f, s3 = 0.f;
        float s4 = 0.f, s5 = 0.f, s6 = 0.f, s7 = 0.f;
#pragma unroll
        for (int c = 0; c < 8; ++c) {
            const int gj = col_base + c;
            const float dot = accv[r][c] * invi * invj[c];
            const float dd = sqrtf(fmaxf(2.f - 2.f * dot, 1e-12f));
            const bool same = (ti == tjc[c]);
            const bool intra = (si == sjc[c]);
            const bool pos = same && (gi != gj);
            const bool neg = !same;
            const float df = (intra ? 2.4f : 2.2f) - dd;
            const float wgt = __expf(df);
            const float v = fmaxf(dd - (intra ? 1.4f : 0.7f), 0.f);
            if (pos && intra)  { s0 += v; s1 += 1.f; }
            if (pos && !intra) { s2 += v; s3 += 1.f; }
            if (neg && intra)  { s4 += df * wgt; s5 += wgt; }
            if (neg && !intra) { s6 += df * wgt; s7 += wgt; }
        }
#pragma unroll
        for (int off = 1; off < 16; off <<= 1) {
            s0 += __shfl_xor(s0, off, 64);
            s1 += __shfl_xor(s1, off, 64);
            s2 += __shfl_xor(s2, off, 64);
            s3 += __shfl_xor(s3, off, 64);
            s4 += __shfl_xor(s4, off, 64);
            s5 += __shfl_xor(s5, off, 64);
            s6 += __shfl_xor(s6, off, 64);
            s7 += __shfl_xor(s7, off, 64);
        }
        if (tx == 0) {
            float* a = acc + (size_t)gi * 8;
            atomicAdd(a + 0, s0); atomicAdd(a + 1, s1);
            atomicAdd(a + 2, s2); atomicAdd(a + 3, s3);
            atomicAdd(a + 4, s4); atomicAdd(a + 5, s5);
            atomicAdd(a + 6, s6); atomicAdd(a + 7, s7);
        }
    }
}

__global__ void finalize_kernel(const float* __restrict__ acc,
                                float* __restrict__ out, int N) {
    float s = 0.f;
    for (int i = threadIdx.x; i < N; i += THREADS) {
        const float* a = acc + (size_t)i * 8;
        s += a[0] / (a[1] + EPSV) + a[2] / (a[3] + EPSV)
           + a[4] / (a[5] + EPSV) + a[6] / (a[7] + EPSV);
    }
#pragma unroll
    for (int off = 32; off > 0; off >>= 1) s += __shfl_down(s, off, 64);
    __shared__ float red[THREADS / 64];
    if ((threadIdx.x & 63) == 0) red[threadIdx.x >> 6] = s;
    __syncthreads();
    if (threadIdx.x == 0) {
        float tot = 0.f;
#pragma unroll
        for (int w = 0; w < THREADS / 64; ++w) tot += red[w];
        out[0] = tot / (float)N;
    }
}

// ---------------------------------------------------------------------------
extern "C" void kernel_launch(void* const* d_in, const int* in_sizes, int n_in,
                              void* d_out, int out_size, void* d_ws, size_t ws_size,
                              hipStream_t stream) {
    const float* x = (const float*)d_in[0];
    const int* targets = (const int*)d_in[1];
    const int* sub = (const int*)d_in[2];
    const int N = in_sizes[1];
    const int D = in_sizes[0] / N;

    const int nbx = N / BM;
    const int T = nbx * (nbx + 1) / 2;
    const size_t sliceB = (size_t)T * 2 * 128 * 8 * sizeof(float);
    const size_t need = (size_t)N * D + 2 * sliceB;   // fp8: N*D bytes

    if (ws_size >= need) {
        unsigned char* xq = (unsigned char*)d_ws;     // N*D fp8
        float* pr = (float*)((char*)d_ws + (size_t)N * D);
        float* pc = pr + (size_t)T * 2 * 128 * 8;

        hipMemsetAsync(d_out, 0, sizeof(float), stream);
        norm_conv_fp8_kernel<<<N, THREADS, 0, stream>>>(x, xq, D);
        gram_fp8_kernel<<<T, THREADS, 0, stream>>>(xq, targets, sub,
                                                   pr, pc, D);
        finalize_sym_kernel<<<N / 16, THREADS, 0, stream>>>(
            pr, pc, (float*)d_out, N, nbx);
    } else {
        // Fallback (144 KB ws): fp32 path, known-good from round 1.
        float* inv_norm = (float*)d_ws;
        float* acc = inv_norm + N;
        hipMemsetAsync(acc, 0, (size_t)N * 8 * sizeof(float), stream);
        row_inv_norm_kernel<<<N, THREADS, 0, stream>>>(x, inv_norm, D);
        dist_loss_kernel<<<nbx * nbx, THREADS, 0, stream>>>(
            x, targets, sub, inv_norm, acc, N, D);
        finalize_kernel<<<1, THREADS, 0, stream>>>(acc, (float*)d_out, N);
    }
}

// Round 18
// 161.336 us; speedup vs baseline: 1.4687x; 1.0271x over previous
//
#include <hip/hip_runtime.h>
#include <math.h>

#define THREADS 256
#define BM 128
#define QBK 128                   // fp8 K per iteration; row slice = 128 B line
#define EPSV 1e-5f
#define C1E 11.023176380641601f   // e^2.4
#define C2E 9.025013499434122f    // e^2.2
#define FP8_SCALE 256.0f          // power-of-2 row scale into e4m3 range
#define INV_SCALE2 1.52587890625e-5f   // 1/65536, exact

typedef float f32x4 __attribute__((ext_vector_type(4)));

// ---------------------------------------------------------------------------
// Kernel A (fp8 path): normalize row, scale by 256, convert to OCP e4m3.
// (R15/R17-proven: absmax 0.0 on the final scalar.)
// ---------------------------------------------------------------------------
__launch_bounds__(THREADS)
__global__ void norm_conv_fp8_kernel(const float* __restrict__ x,
                                     unsigned char* __restrict__ xq, int D) {
    const int row = blockIdx.x;
    const float4* x4 = (const float4*)(x + (size_t)row * D);
    const int tid = threadIdx.x;

    float s = 0.f;
    for (int b = tid * 2; b * 4 < D; b += THREADS * 2) {
        float4 v0 = x4[b];
        float4 v1 = x4[b + 1];
        s += v0.x * v0.x + v0.y * v0.y + v0.z * v0.z + v0.w * v0.w
           + v1.x * v1.x + v1.y * v1.y + v1.z * v1.z + v1.w * v1.w;
    }
#pragma unroll
    for (int off = 32; off > 0; off >>= 1) s += __shfl_down(s, off, 64);
    __shared__ float red[THREADS / 64 + 1];
    if ((tid & 63) == 0) red[tid >> 6] = s;
    __syncthreads();
    if (tid == 0) {
        float tot = 0.f;
#pragma unroll
        for (int w = 0; w < THREADS / 64; ++w) tot += red[w];
        red[THREADS / 64] = FP8_SCALE / fmaxf(sqrtf(tot), 1e-12f);
    }
    __syncthreads();
    const float sc = red[THREADS / 64];

    int2* out = (int2*)(xq + (size_t)row * D);
    for (int b = tid * 2; b * 4 < D; b += THREADS * 2) {
        float4 v0 = x4[b];
        float4 v1 = x4[b + 1];
        int lo = __builtin_amdgcn_cvt_pk_fp8_f32(v0.x * sc, v0.y * sc, 0, 0);
        lo = __builtin_amdgcn_cvt_pk_fp8_f32(v0.z * sc, v0.w * sc, lo, 1);
        int hi = __builtin_amdgcn_cvt_pk_fp8_f32(v1.x * sc, v1.y * sc, 0, 0);
        hi = __builtin_amdgcn_cvt_pk_fp8_f32(v1.z * sc, v1.w * sc, hi, 1);
        int2 o; o.x = lo; o.y = hi;
        out[b >> 1] = o;
    }
}

// Plain inv-norm (fallback path).
__global__ void row_inv_norm_kernel(const float* __restrict__ x,
                                    float* __restrict__ inv_norm, int D) {
    const int row = blockIdx.x;
    const float4* x4 = (const float4*)(x + (size_t)row * D);
    const int nf4 = D >> 2;
    float s = 0.f;
    for (int i = threadIdx.x; i < nf4; i += THREADS) {
        float4 v = x4[i];
        s += v.x * v.x + v.y * v.y + v.z * v.z + v.w * v.w;
    }
#pragma unroll
    for (int off = 32; off > 0; off >>= 1) s += __shfl_down(s, off, 64);
    __shared__ float red[THREADS / 64];
    if ((threadIdx.x & 63) == 0) red[threadIdx.x >> 6] = s;
    __syncthreads();
    if (threadIdx.x == 0) {
        float tot = 0.f;
#pragma unroll
        for (int w = 0; w < THREADS / 64; ++w) tot += red[w];
        inv_norm[row] = 1.0f / fmaxf(sqrtf(tot), 1e-12f);
    }
}

#define GLDS16(g, l)                                                          \
    __builtin_amdgcn_global_load_lds(                                         \
        (const __attribute__((address_space(1))) unsigned int*)(g),           \
        (__attribute__((address_space(3))) unsigned int*)(l), 16, 0, 0)

// ---------------------------------------------------------------------------
// Kernel B: SYMMETRIC fp8 Gram, BK=128 full-line staging (R17) + DOUBLE-
// BUFFERED glds pipeline. R10's dbuf was neutral at BK=32 because the
// compute phase (~150 cyc/wave) couldn't cover the ~900 cyc drain; R17's
// iterations carry 64 MFMAs/wave (~4x fatter), so the prefetch issued
// before the MFMA block now has real work to hide behind. One barrier per
// iteration (tail): drains the prefetch + guards buf reuse.
// LDS 2 x (16+16) KB = 64 KB -> still 2 blocks/CU (128 <= 160).
// vals: 0 s_pos_intra 1 cnt_pi 2 s_pos_cross 3 cnt_pc
//       4 DE_neg_intra 5 E_neg_intra 6 DE_neg_cross 7 E_neg_cross
// ---------------------------------------------------------------------------
__launch_bounds__(THREADS, 2)
__global__ void gram_fp8_kernel(const unsigned char* __restrict__ xq,
                                const int* __restrict__ targets,
                                const int* __restrict__ sub,
                                float* __restrict__ pr,
                                float* __restrict__ pc,
                                int D) {
    __shared__ unsigned char As[2][BM * QBK];   // 2 x 16 KB
    __shared__ unsigned char Bs[2][BM * QBK];   // 2 x 16 KB

    // Triangular decode: tk = bx*(bx+1)/2 + by, by <= bx.
    const int tk = blockIdx.x;
    int bx = (int)((sqrtf(8.0f * tk + 1.0f) - 1.0f) * 0.5f);
    while ((bx + 1) * (bx + 2) / 2 <= tk) ++bx;
    while (bx * (bx + 1) / 2 > tk) --bx;
    const int by = tk - bx * (bx + 1) / 2;

    const int tid = threadIdx.x;
    const int w = tid >> 6;          // wave 0..3
    const int lane = tid & 63;
    const int wm = w & 1;            // row-half
    const int wn = w >> 1;           // col-half
    const int quad = lane >> 4;
    const int cl = lane & 15;

    const int rowA0 = by * BM;
    const int colB0 = bx * BM;
    const unsigned char* Abase = xq + (size_t)rowA0 * D;
    const unsigned char* Bbase = xq + (size_t)colB0 * D;

    // Staging: tile = 128 rows x 8 chunks of 16B = 1024 chunks per matrix.
    // Thread covers chunks l*256+tid (l=0..3) per matrix -> 8 glds/iter.
    // Dst chunk c: row r=c>>3, slot q=c&7; source slot q' = q ^ (r&7).
    const unsigned char* sA[4];
    const unsigned char* sB[4];
    int dof[4];
#pragma unroll
    for (int l = 0; l < 4; ++l) {
        const int c = l * 256 + tid;
        const int r = c >> 3, q = (c & 7) ^ ((c >> 3) & 7);
        sA[l] = Abase + (size_t)r * D + q * 16;
        sB[l] = Bbase + (size_t)r * D + q * 16;
        dof[l] = (l * 256 + w * 64) * 16;   // wave-uniform byte base
    }

    f32x4 accv[4][4];
#pragma unroll
    for (int i = 0; i < 4; ++i)
#pragma unroll
        for (int j = 0; j < 4; ++j) accv[i][j] = (f32x4)(0.f);

    // Fragment byte offsets: row r, K-step ks: 8B slot sl = ks*4+quad;
    // chunk sl>>1 stored at (sl>>1)^(r&7); byte = r*128 + chunk'*16 +
    // (sl&1)*8.
    int aoff[4][4], boff[4][4];
#pragma unroll
    for (int f = 0; f < 4; ++f) {
        const int ar = wm * 64 + f * 16 + cl;
        const int br = wn * 64 + f * 16 + cl;
#pragma unroll
        for (int ks = 0; ks < 4; ++ks) {
            const int sl = ks * 4 + quad;
            aoff[f][ks] = ar * QBK + (((sl >> 1) ^ (ar & 7)) << 4)
                        + ((sl & 1) << 3);
            boff[f][ks] = br * QBK + (((sl >> 1) ^ (br & 7)) << 4)
                        + ((sl & 1) << 3);
        }
    }

    const int nIter = D / QBK;

    // Prologue: stage tile 0 into buf 0 (one unavoidable full drain).
#pragma unroll
    for (int l = 0; l < 4; ++l) {
        GLDS16(sA[l], &As[0][0] + dof[l]);
        GLDS16(sB[l], &Bs[0][0] + dof[l]);
    }
    __syncthreads();

    for (int it = 0; it < nIter; ++it) {
        const int cur = it & 1;
        const int nxt = cur ^ 1;

        // Prefetch tile it+1 into the other buffer BEFORE computing tile it.
        if (it + 1 < nIter) {
            const int kb = (it + 1) * QBK;
#pragma unroll
            for (int l = 0; l < 4; ++l) {
                GLDS16(sA[l] + kb, &As[nxt][0] + dof[l]);
                GLDS16(sB[l] + kb, &Bs[nxt][0] + dof[l]);
            }
        }

#pragma unroll
        for (int ks = 0; ks < 4; ++ks) {
            long af[4], bfv[4];
#pragma unroll
            for (int f = 0; f < 4; ++f) {
                af[f] = *(const long*)&As[cur][aoff[f][ks]];
                bfv[f] = *(const long*)&Bs[cur][boff[f][ks]];
            }
#pragma unroll
            for (int mi = 0; mi < 4; ++mi)
#pragma unroll
                for (int ni = 0; ni < 4; ++ni)
                    accv[mi][ni] =
                        __builtin_amdgcn_mfma_f32_16x16x32_fp8_fp8(
                            af[mi], bfv[ni], accv[mi][ni], 0, 0, 0);
        }
        __syncthreads();   // drains prefetch (compute phase was in flight)
                           // + guards buf[cur] reuse next iteration
    }

    // ---------------- epilogue pass 1: dd + row partials ----------------
    // C/D map: col = cl, row = quad*4 + reg. Dots carry scale 65536.
    int tj[4], sj[4];
#pragma unroll
    for (int ni = 0; ni < 4; ++ni) {
        const int gc = colB0 + wn * 64 + ni * 16 + cl;
        tj[ni] = targets[gc];
        sj[ni] = sub[gc];
    }

#pragma unroll
    for (int mi = 0; mi < 4; ++mi) {
#pragma unroll
        for (int r = 0; r < 4; ++r) {
            const int gi = rowA0 + wm * 64 + mi * 16 + quad * 4 + r;
            const int ti = targets[gi];
            const int si = sub[gi];

            float s0 = 0.f, s1 = 0.f, s2 = 0.f, s3 = 0.f;
            float s4 = 0.f, s5 = 0.f, s6 = 0.f, s7 = 0.f;
#pragma unroll
            for (int ni = 0; ni < 4; ++ni) {
                const int gj = colB0 + wn * 64 + ni * 16 + cl;
                const float d2 =
                    fmaf(-2.0f * INV_SCALE2, accv[mi][ni][r], 2.0f);
                const float dd = sqrtf(fmaxf(d2, 1e-12f));
                accv[mi][ni][r] = dd;          // overwrite: pass 2 reuses
                const bool same = (ti == tj[ni]);
                const bool intra = (si == sj[ni]);
                const bool pos = same && (gi != gj);
                const bool neg = !same;
                const float mg = intra ? 1.4f : 0.7f;
                const float v = fmaxf(dd - mg, 0.f);
                const float e = __expf(-dd);   // e^alpha folded in finalize
                const float de = dd * e;
                if (pos && intra)  { s0 += v;  s1 += 1.f; }
                if (pos && !intra) { s2 += v;  s3 += 1.f; }
                if (neg && intra)  { s4 += de; s5 += e; }
                if (neg && !intra) { s6 += de; s7 += e; }
            }
#pragma unroll
            for (int off = 1; off < 16; off <<= 1) {
                s0 += __shfl_xor(s0, off, 64);
                s1 += __shfl_xor(s1, off, 64);
                s2 += __shfl_xor(s2, off, 64);
                s3 += __shfl_xor(s3, off, 64);
                s4 += __shfl_xor(s4, off, 64);
                s5 += __shfl_xor(s5, off, 64);
                s6 += __shfl_xor(s6, off, 64);
                s7 += __shfl_xor(s7, off, 64);
            }
            if (cl == 0) {
                const int rloc = wm * 64 + mi * 16 + quad * 4 + r;
                float* dst = pr +
                    ((size_t)(blockIdx.x * 2 + wn) * 128 + rloc) * 8;
                float4 p0 = {s0, s1, s2, s3};
                float4 p1 = {s4, s5, s6, s7};
                *(float4*)(dst) = p0;
                *(float4*)(dst + 4) = p1;
            }
        }
    }

    // ---------------- epilogue pass 2: col partials ----------------
    const float om = (bx == by) ? 0.f : 1.f;   // diag tiles: zero col side
#pragma unroll
    for (int ni = 0; ni < 4; ++ni) {
        const int gj = colB0 + wn * 64 + ni * 16 + cl;
        const int tjc = tj[ni];
        const int sjc = sj[ni];
        float s0 = 0.f, s1 = 0.f, s2 = 0.f, s3 = 0.f;
        float s4 = 0.f, s5 = 0.f, s6 = 0.f, s7 = 0.f;
#pragma unroll
        for (int mi = 0; mi < 4; ++mi) {
#pragma unroll
            for (int r = 0; r < 4; ++r) {
                const int gi = rowA0 + wm * 64 + mi * 16 + quad * 4 + r;
                const int ti = targets[gi];     // L1-hot reload
                const int si = sub[gi];
                const float dd = accv[mi][ni][r];
                const bool same = (ti == tjc);
                const bool intra = (si == sjc);
                const bool pos = same && (gi != gj);
                const bool neg = !same;
                const float mg = intra ? 1.4f : 0.7f;
                const float v = fmaxf(dd - mg, 0.f);
                const float e = __expf(-dd);
                const float de = dd * e;
                if (pos && intra)  { s0 += v;  s1 += 1.f; }
                if (pos && !intra) { s2 += v;  s3 += 1.f; }
                if (neg && intra)  { s4 += de; s5 += e; }
                if (neg && !intra) { s6 += de; s7 += e; }
            }
        }
        s0 += __shfl_xor(s0, 16, 64); s0 += __shfl_xor(s0, 32, 64);
        s1 += __shfl_xor(s1, 16, 64); s1 += __shfl_xor(s1, 32, 64);
        s2 += __shfl_xor(s2, 16, 64); s2 += __shfl_xor(s2, 32, 64);
        s3 += __shfl_xor(s3, 16, 64); s3 += __shfl_xor(s3, 32, 64);
        s4 += __shfl_xor(s4, 16, 64); s4 += __shfl_xor(s4, 32, 64);
        s5 += __shfl_xor(s5, 16, 64); s5 += __shfl_xor(s5, 32, 64);
        s6 += __shfl_xor(s6, 16, 64); s6 += __shfl_xor(s6, 32, 64);
        s7 += __shfl_xor(s7, 16, 64); s7 += __shfl_xor(s7, 32, 64);
        if (lane < 16) {
            const int colloc = wn * 64 + ni * 16 + lane;
            float* dst = pc +
                ((size_t)(blockIdx.x * 2 + wm) * 128 + colloc) * 8;
            float4 p0 = {s0 * om, s1 * om, s2 * om, s3 * om};
            float4 p1 = {s4 * om, s5 * om, s6 * om, s7 * om};
            *(float4*)(dst) = p0;
            *(float4*)(dst + 4) = p1;
        }
    }
}

// ---------------------------------------------------------------------------
// Kernel C: gather 64 slices per row, combine ratios, global mean.
// ---------------------------------------------------------------------------
__global__ void finalize_sym_kernel(const float* __restrict__ pr,
                                    const float* __restrict__ pc,
                                    float* __restrict__ out, int N, int nbx) {
    const int tid = threadIdx.x;
    const int rloc16 = tid >> 4;
    const int st = tid & 15;
    const int i = blockIdx.x * 16 + rloc16;
    const int B = i >> 7;
    const int rl = i & 127;
    const int nrow = (nbx - B) * 2;

    float a0 = 0.f, a1 = 0.f, a2 = 0.f, a3 = 0.f;
    float a4 = 0.f, a5 = 0.f, a6 = 0.f, a7 = 0.f;
#pragma unroll
    for (int s4i = 0; s4i < 4; ++s4i) {
        const int sidx = st * 4 + s4i;
        const float* base;
        if (sidx < nrow) {
            const int bxx = B + (sidx >> 1);
            const int t = bxx * (bxx + 1) / 2 + B;
            base = pr + ((size_t)(t * 2 + (sidx & 1)) * 128 + rl) * 8;
        } else {
            const int m = sidx - nrow;
            const int t = B * (B + 1) / 2 + (m >> 1);
            base = pc + ((size_t)(t * 2 + (m & 1)) * 128 + rl) * 8;
        }
        float4 u0 = *(const float4*)(base);
        float4 u1 = *(const float4*)(base + 4);
        a0 += u0.x; a1 += u0.y; a2 += u0.z; a3 += u0.w;
        a4 += u1.x; a5 += u1.y; a6 += u1.z; a7 += u1.w;
    }
#pragma unroll
    for (int off = 1; off < 16; off <<= 1) {
        a0 += __shfl_xor(a0, off, 64);
        a1 += __shfl_xor(a1, off, 64);
        a2 += __shfl_xor(a2, off, 64);
        a3 += __shfl_xor(a3, off, 64);
        a4 += __shfl_xor(a4, off, 64);
        a5 += __shfl_xor(a5, off, 64);
        a6 += __shfl_xor(a6, off, 64);
        a7 += __shfl_xor(a7, off, 64);
    }
    __shared__ float lred[16];
    if (st == 0) {
        const float l = a0 / (a1 + EPSV) + a2 / (a3 + EPSV)
            + (C1E * fmaf(2.4f, a5, -a4)) / (C1E * a5 + EPSV)
            + (C2E * fmaf(2.2f, a7, -a6)) / (C2E * a7 + EPSV);
        lred[rloc16] = l;
    }
    __syncthreads();
    if (tid == 0) {
        float tot = 0.f;
#pragma unroll
        for (int k2 = 0; k2 < 16; ++k2) tot += lred[k2];
        atomicAdd(out, tot / (float)N);
    }
}

// ---------------------------------------------------------------------------
// Fallback path (144 KB ws): fp32 tile GEMM + atomic epilogue (R1, known-good)
// ---------------------------------------------------------------------------
__launch_bounds__(THREADS, 2)
__global__ void dist_loss_kernel(const float* __restrict__ x,
                                 const int* __restrict__ targets,
                                 const int* __restrict__ sub,
                                 const float* __restrict__ inv_norm,
                                 float* __restrict__ acc,
                                 int N, int D) {
    __shared__ float Asf[16][128];
    __shared__ float Bsf[16][128];

    const int nbx = N / 128;
    const int bx = blockIdx.x % nbx;
    const int by = blockIdx.x / nbx;
    const int tid = threadIdx.x;
    const int tx = tid & 15;
    const int ty = tid >> 4;
    const int rowA0 = by * 128;
    const int colB0 = bx * 128;
    const float* Abase = x + (size_t)rowA0 * D;
    const float* Bbase = x + (size_t)colB0 * D;

    float accv[8][8];
#pragma unroll
    for (int r = 0; r < 8; ++r)
#pragma unroll
        for (int c = 0; c < 8; ++c) accv[r][c] = 0.f;

    for (int kb = 0; kb < D; kb += 16) {
#pragma unroll
        for (int l = 0; l < 2; ++l) {
            const int f = tid + l * THREADS;
            const int row = f >> 2;
            const int kq = (f & 3) << 2;
            float4 va = *(const float4*)(Abase + (size_t)row * D + kb + kq);
            float4 vb = *(const float4*)(Bbase + (size_t)row * D + kb + kq);
            Asf[kq + 0][row] = va.x; Asf[kq + 1][row] = va.y;
            Asf[kq + 2][row] = va.z; Asf[kq + 3][row] = va.w;
            Bsf[kq + 0][row] = vb.x; Bsf[kq + 1][row] = vb.y;
            Bsf[kq + 2][row] = vb.z; Bsf[kq + 3][row] = vb.w;
        }
        __syncthreads();
#pragma unroll
        for (int k = 0; k < 16; ++k) {
            float4 a0 = *(const float4*)&Asf[k][ty * 8];
            float4 a1 = *(const float4*)&Asf[k][ty * 8 + 4];
            float4 b0 = *(const float4*)&Bsf[k][tx * 8];
            float4 b1 = *(const float4*)&Bsf[k][tx * 8 + 4];
            float ar[8] = {a0.x, a0.y, a0.z, a0.w, a1.x, a1.y, a1.z, a1.w};
            float br[8] = {b0.x, b0.y, b0.z, b0.w, b1.x, b1.y, b1.z, b1.w};
#pragma unroll
            for (int r = 0; r < 8; ++r)
#pragma unroll
                for (int c = 0; c < 8; ++c)
                    accv[r][c] = fmaf(ar[r], br[c], accv[r][c]);
        }
        __syncthreads();
    }

    const int row_base = rowA0 + ty * 8;
    const int col_base = colB0 + tx * 8;
    int tjc[8], sjc[8];
    float invj[8];
#pragma unroll
    for (int c = 0; c < 8; ++c) {
        tjc[c] = targets[col_base + c];
        sjc[c] = sub[col_base + c];
        invj[c] = inv_norm[col_base + c];
    }
#pragma unroll
    for (int r = 0; r < 8; ++r) {
        const int gi = row_base + r;
        const int ti = targets[gi];
        const int si = sub[gi];
        const float invi = inv_norm[gi];
        float s0 = 0.f, s1 = 0.f, s2 = 0.f, s3 = 0.f;
        float s4 = 0.f, s5 = 0.f, s6 = 0.f, s7 = 0.f;
#pragma unroll
        for (int c = 0; c < 8; ++c) {
            const int gj = col_base + c;
            const float dot = accv[r][c] * invi * invj[c];
            const float dd = sqrtf(fmaxf(2.f - 2.f * dot, 1e-12f));
            const bool same = (ti == tjc[c]);
            const bool intra = (si == sjc[c]);
            const bool pos = same && (gi != gj);
            const bool neg = !same;
            const float df = (intra ? 2.4f : 2.2f) - dd;
            const float wgt = __expf(df);
            const float v = fmaxf(dd - (intra ? 1.4f : 0.7f), 0.f);
            if (pos && intra)  { s0 += v; s1 += 1.f; }
            if (pos && !intra) { s2 += v; s3 += 1.f; }
            if (neg && intra)  { s4 += df * wgt; s5 += wgt; }
            if (neg && !intra) { s6 += df * wgt; s7 += wgt; }
        }
#pragma unroll
        for (int off = 1; off < 16; off <<= 1) {
            s0 += __shfl_xor(s0, off, 64);
            s1 += __shfl_xor(s1, off, 64);
            s2 += __shfl_xor(s2, off, 64);
            s3 += __shfl_xor(s3, off, 64);
            s4 += __shfl_xor(s4, off, 64);
            s5 += __shfl_xor(s5, off, 64);
            s6 += __shfl_xor(s6, off, 64);
            s7 += __shfl_xor(s7, off, 64);
        }
        if (tx == 0) {
            float* a = acc + (size_t)gi * 8;
            atomicAdd(a + 0, s0); atomicAdd(a + 1, s1);
            atomicAdd(a + 2, s2); atomicAdd(a + 3, s3);
            atomicAdd(a + 4, s4); atomicAdd(a + 5, s5);
            atomicAdd(a + 6, s6); atomicAdd(a + 7, s7);
        }
    }
}

__global__ void finalize_kernel(const float* __restrict__ acc,
                                float* __restrict__ out, int N) {
    float s = 0.f;
    for (int i = threadIdx.x; i < N; i += THREADS) {
        const float* a = acc + (size_t)i * 8;
        s += a[0] / (a[1] + EPSV) + a[2] / (a[3] + EPSV)
           + a[4] / (a[5] + EPSV) + a[6] / (a[7] + EPSV);
    }
#pragma unroll
    for (int off = 32; off > 0; off >>= 1) s += __shfl_down(s, off, 64);
    __shared__ float red[THREADS / 64];
    if ((threadIdx.x & 63) == 0) red[threadIdx.x >> 6] = s;
    __syncthreads();
    if (threadIdx.x == 0) {
        float tot = 0.f;
#pragma unroll
        for (int w = 0; w < THREADS / 64; ++w) tot += red[w];
        out[0] = tot / (float)N;
    }
}

// ---------------------------------------------------------------------------
extern "C" void kernel_launch(void* const* d_in, const int* in_sizes, int n_in,
                              void* d_out, int out_size, void* d_ws, size_t ws_size,
                              hipStream_t stream) {
    const float* x = (const float*)d_in[0];
    const int* targets = (const int*)d_in[1];
    const int* sub = (const int*)d_in[2];
    const int N = in_sizes[1];
    const int D = in_sizes[0] / N;

    const int nbx = N / BM;
    const int T = nbx * (nbx + 1) / 2;
    const size_t sliceB = (size_t)T * 2 * 128 * 8 * sizeof(float);
    const size_t need = (size_t)N * D + 2 * sliceB;   // fp8: N*D bytes

    if (ws_size >= need) {
        unsigned char* xq = (unsigned char*)d_ws;     // N*D fp8
        float* pr = (float*)((char*)d_ws + (size_t)N * D);
        float* pc = pr + (size_t)T * 2 * 128 * 8;

        hipMemsetAsync(d_out, 0, sizeof(float), stream);
        norm_conv_fp8_kernel<<<N, THREADS, 0, stream>>>(x, xq, D);
        gram_fp8_kernel<<<T, THREADS, 0, stream>>>(xq, targets, sub,
                                                   pr, pc, D);
        finalize_sym_kernel<<<N / 16, THREADS, 0, stream>>>(
            pr, pc, (float*)d_out, N, nbx);
    } else {
        // Fallback (144 KB ws): fp32 path, known-good from round 1.
        float* inv_norm = (float*)d_ws;
        float* acc = inv_norm + N;
        hipMemsetAsync(acc, 0, (size_t)N * 8 * sizeof(float), stream);
        row_inv_norm_kernel<<<N, THREADS, 0, stream>>>(x, inv_norm, D);
        dist_loss_kernel<<<nbx * nbx, THREADS, 0, stream>>>(
            x, targets, sub, inv_norm, acc, N, D);
        finalize_kernel<<<1, THREADS, 0, stream>>>(acc, (float*)d_out, N);
    }
}